// Round 3
// baseline (1556.194 us; speedup 1.0000x reference)
//
#include <hip/hip_runtime.h>
#include <hip/hip_bf16.h>
#include <math.h>

typedef unsigned short u16;
typedef u16 us8 __attribute__((ext_vector_type(8)));
typedef __bf16 bf8 __attribute__((ext_vector_type(8)));
typedef float f32x4 __attribute__((ext_vector_type(4)));

#define SCAN_B 256

__device__ __forceinline__ float bf2f(u16 v) {
    unsigned u = ((unsigned)v) << 16;
    return __builtin_bit_cast(float, u);
}
__device__ __forceinline__ u16 f2bf(float f) {
    // round-to-nearest-even bf16
    unsigned u = __builtin_bit_cast(unsigned, f);
    unsigned lsb = (u >> 16) & 1;
    u += 0x7fff + lsb;
    return (u16)(u >> 16);
}

// ---------------- runtime dtype probes ----------------
// flag[0]: edge_index is int64 (1) vs int32 (0)
// flag[1]: float tensors are float32 (1) vs bfloat16 (0)
__global__ void detect_k(const int* __restrict__ ei, int E,
                         const u16* __restrict__ xraw, int* flag) {
    __shared__ int c_i32, c_f32;
    if (threadIdx.x == 0) { c_i32 = 0; c_f32 = 0; }
    __syncthreads();
    int ne = (E < 4096) ? E : 4096;
    for (int e = threadIdx.x; e < ne; e += blockDim.x)
        if (ei[2 * e + 1] != 0) c_i32 = 1;   // int32 data: odd elements are node ids
    for (int k = threadIdx.x; k < 8192; k += blockDim.x) {
        u16 v = xraw[2 * k];                 // even u16: bf16 value OR f32 low-mantissa garbage
        int ex = (v >> 7) & 0xFF;
        if (ex >= 0xF0) atomicAdd(&c_f32, 1);
    }
    __syncthreads();
    if (threadIdx.x == 0) {
        flag[0] = (c_i32 == 0) ? 1 : 0;
        flag[1] = (c_f32 >= 4) ? 1 : 0;
    }
}

// ---------------- canonicalize inputs ----------------
// x (either float dtype) -> bf16 buffer
__global__ void cvt_x_k(const void* __restrict__ src, u16* __restrict__ dst,
                        long n, const int* __restrict__ flag) {
    int f32m = flag[1];
    long i0 = (long)blockIdx.x * blockDim.x + threadIdx.x;
    long stride = (long)gridDim.x * blockDim.x;
    if (f32m) {
        const float* s = (const float*)src;
        for (long i = i0; i < n; i += stride) dst[i] = f2bf(s[i]);
    } else {
        const u16* s = (const u16*)src;
        for (long i = i0; i < n; i += stride) dst[i] = s[i];
    }
}

// weight W[K,Nn] (either dtype) -> transposed bf16 Wt[Nn,K]
__global__ void cvt_wt_k(const void* __restrict__ W, u16* __restrict__ Wt,
                         int K, int Nn, const int* __restrict__ flag) {
    int t = blockIdx.x * blockDim.x + threadIdx.x;
    if (t >= K * Nn) return;
    int k = t / Nn, nn = t - k * Nn;
    u16 b;
    if (flag[1]) b = f2bf(((const float*)W)[t]);
    else         b = ((const u16*)W)[t];
    Wt[nn * K + k] = b;
}

// small param vectors (either dtype) -> f32 staging buffer
struct PEnt { const void* s; int n; int off; };
struct PTab { PEnt e[14]; };
__global__ void cvt_params_k(PTab tab, float* __restrict__ pbuf,
                             const int* __restrict__ flag) {
    PEnt en = tab.e[blockIdx.x];
    int f32m = flag[1];
    for (int i = threadIdx.x; i < en.n; i += blockDim.x) {
        float v = f32m ? ((const float*)en.s)[i] : bf2f(((const u16*)en.s)[i]);
        pbuf[en.off + i] = v;
    }
}

// ---------------- CSR build ----------------
__global__ void init_counts_k(int* counts, int n) {
    int i = blockIdx.x * blockDim.x + threadIdx.x;
    if (i < n) counts[i] = 1;  // self-loop
}

__global__ void count_edges_k(const int* __restrict__ ei, const int* __restrict__ flag,
                              int* counts, int E, int n) {
    int e = blockIdx.x * blockDim.x + threadIdx.x;
    if (e >= E) return;
    int d;
    if (flag[0]) d = (int)((const long long*)ei)[(size_t)E + e];
    else         d = ei[(size_t)E + e];
    if ((unsigned)d < (unsigned)n) atomicAdd(&counts[d], 1);
}

__global__ void dinv_k(const int* __restrict__ counts, float* dinv, int n) {
    int i = blockIdx.x * blockDim.x + threadIdx.x;
    if (i < n) dinv[i] = rsqrtf((float)counts[i]);
}

__global__ void scan1_k(const int* __restrict__ counts, int* incl, int* bsum, int n) {
    __shared__ int tmp[SCAN_B];
    int t = threadIdx.x;
    int i = blockIdx.x * SCAN_B + t;
    int v = (i < n) ? counts[i] : 0;
    tmp[t] = v;
    __syncthreads();
    for (int o = 1; o < SCAN_B; o <<= 1) {
        int x = 0;
        if (t >= o) x = tmp[t - o];
        __syncthreads();
        if (t >= o) tmp[t] += x;
        __syncthreads();
    }
    if (i < n) incl[i] = tmp[t];
    if (t == SCAN_B - 1) bsum[blockIdx.x] = tmp[t];
}

__global__ void scan2_k(const int* __restrict__ bsum, int* bscan, int nb) {
    __shared__ int tmp[SCAN_B];
    int t = threadIdx.x;
    tmp[t] = (t < nb) ? bsum[t] : 0;
    __syncthreads();
    for (int o = 1; o < SCAN_B; o <<= 1) {
        int x = 0;
        if (t >= o) x = tmp[t - o];
        __syncthreads();
        if (t >= o) tmp[t] += x;
        __syncthreads();
    }
    bscan[t] = tmp[t];
}

__global__ void rowptr_k(const int* __restrict__ incl, const int* __restrict__ bscan,
                         int* rowptr, int n) {
    int i = blockIdx.x * blockDim.x + threadIdx.x;
    if (i < n) {
        int boff = (blockIdx.x > 0) ? bscan[blockIdx.x - 1] : 0;
        rowptr[i + 1] = incl[i] + boff;
        if (i == 0) rowptr[0] = 0;
    }
}

__global__ void cursor_k(const int* __restrict__ rowptr, int* cursor, int n) {
    int i = blockIdx.x * blockDim.x + threadIdx.x;
    if (i < n) cursor[i] = rowptr[i];
}

__global__ void scatter_k(const int* __restrict__ ei, const int* __restrict__ flag,
                          int* cursor, int* col, int E, int n) {
    int e = blockIdx.x * blockDim.x + threadIdx.x;
    if (e < E) {
        int s, d;
        if (flag[0]) {
            const long long* e64 = (const long long*)ei;
            s = (int)e64[e]; d = (int)e64[(size_t)E + e];
        } else {
            s = ei[e]; d = ei[(size_t)E + e];
        }
        if ((unsigned)s < (unsigned)n && (unsigned)d < (unsigned)n) {
            int pos = atomicAdd(&cursor[d], 1);
            col[pos] = s;
        }
    } else if (e < E + n) {
        int i = e - E;
        int pos = atomicAdd(&cursor[i], 1);
        col[pos] = i;
    }
}

// ---------------- bf16 MFMA GEMM: C[M,Nn] = A[M,K] * Bt[Nn,K]^T ----------------
#define TM 64
#define TN 64
#define BK 32
#define LDSS 40

__global__ __launch_bounds__(256) void gemm_bt_k(
    const u16* __restrict__ A, const u16* __restrict__ Bt,
    u16* __restrict__ C, int M, int K, int Nn) {
    __shared__ u16 As[TM * LDSS];
    __shared__ u16 Bs[TN * LDSS];
    int tid = threadIdx.x;
    int wave = tid >> 6;
    int lane = tid & 63;
    int wm = (wave & 1) * 32;
    int wn = (wave >> 1) * 32;
    int row0 = blockIdx.x * TM;
    int col0 = blockIdx.y * TN;

    f32x4 acc00 = {0.f, 0.f, 0.f, 0.f}, acc01 = acc00, acc10 = acc00, acc11 = acc00;

    int lrow = tid >> 2;
    int lcol = (tid & 3) * 8;
    int q = lane >> 4;
    int m = lane & 15;

    for (int k0 = 0; k0 < K; k0 += BK) {
        int gr = row0 + lrow;
        us8 va = (us8)0;
        if (gr < M) va = *(const us8*)(A + (size_t)gr * K + k0 + lcol);
        *(us8*)(&As[lrow * LDSS + lcol]) = va;
        int gc = col0 + lrow;
        us8 vb = (us8)0;
        if (gc < Nn) vb = *(const us8*)(Bt + (size_t)gc * K + k0 + lcol);
        *(us8*)(&Bs[lrow * LDSS + lcol]) = vb;
        __syncthreads();

        us8 a0 = *(const us8*)(&As[(wm + m) * LDSS + q * 8]);
        us8 a1 = *(const us8*)(&As[(wm + 16 + m) * LDSS + q * 8]);
        us8 b0 = *(const us8*)(&Bs[(wn + m) * LDSS + q * 8]);
        us8 b1 = *(const us8*)(&Bs[(wn + 16 + m) * LDSS + q * 8]);
        bf8 fa0 = __builtin_bit_cast(bf8, a0);
        bf8 fa1 = __builtin_bit_cast(bf8, a1);
        bf8 fb0 = __builtin_bit_cast(bf8, b0);
        bf8 fb1 = __builtin_bit_cast(bf8, b1);
        acc00 = __builtin_amdgcn_mfma_f32_16x16x32_bf16(fa0, fb0, acc00, 0, 0, 0);
        acc01 = __builtin_amdgcn_mfma_f32_16x16x32_bf16(fa0, fb1, acc01, 0, 0, 0);
        acc10 = __builtin_amdgcn_mfma_f32_16x16x32_bf16(fa1, fb0, acc10, 0, 0, 0);
        acc11 = __builtin_amdgcn_mfma_f32_16x16x32_bf16(fa1, fb1, acc11, 0, 0, 0);
        __syncthreads();
    }

    int cn = lane & 15;
    // C/D layout: col = lane&15, row = (lane>>4)*4 + r  [measured m89]
    #pragma unroll
    for (int r = 0; r < 4; r++) {
        int rr = q * 4 + r;
        int row_a = row0 + wm + rr;
        int row_b = row0 + wm + 16 + rr;
        if (row_a < M) {
            C[(size_t)row_a * Nn + col0 + wn + cn] = f2bf(acc00[r]);
            C[(size_t)row_a * Nn + col0 + wn + 16 + cn] = f2bf(acc01[r]);
        }
        if (row_b < M) {
            C[(size_t)row_b * Nn + col0 + wn + cn] = f2bf(acc10[r]);
            C[(size_t)row_b * Nn + col0 + wn + 16 + cn] = f2bf(acc11[r]);
        }
    }
}

// ---------------- fused aggregate + bias [+ LN + ELU (+resid)] ----------------
// grid = N nodes, blockDim = F.
// norm factored: sum_e dinv[s]*dinv[i]*xw[s] = dinv[i] * sum_e dinv[s]*xw[s]
// stage_conv: internal bf16 staging (layer 2 halves), stride stage_ldo.
// final_base: if non-null, write conv/bn into d_out (dtype per flag[1]).
__global__ void agg_ln_elu_k(
    const u16* __restrict__ xw, const int* __restrict__ rowptr,
    const int* __restrict__ col, const float* __restrict__ dinv,
    const float* __restrict__ bias, const float* __restrict__ gamma,
    const float* __restrict__ beta, u16* __restrict__ out_h,
    const u16* __restrict__ resid, u16* __restrict__ stage_conv, int stage_ldo,
    void* __restrict__ final_base, const int* __restrict__ flag, int F, int nN) {
    int i = blockIdx.x;
    int f = threadIdx.x;
    int beg = rowptr[i], end = rowptr[i + 1];
    float a0 = 0.f, a1 = 0.f, a2 = 0.f, a3 = 0.f;
    int e = beg;
    for (; e + 3 < end; e += 4) {
        int s0 = col[e], s1 = col[e + 1], s2 = col[e + 2], s3 = col[e + 3];
        s0 = ((unsigned)s0 < (unsigned)nN) ? s0 : 0;
        s1 = ((unsigned)s1 < (unsigned)nN) ? s1 : 0;
        s2 = ((unsigned)s2 < (unsigned)nN) ? s2 : 0;
        s3 = ((unsigned)s3 < (unsigned)nN) ? s3 : 0;
        a0 += dinv[s0] * bf2f(xw[(size_t)s0 * F + f]);
        a1 += dinv[s1] * bf2f(xw[(size_t)s1 * F + f]);
        a2 += dinv[s2] * bf2f(xw[(size_t)s2 * F + f]);
        a3 += dinv[s3] * bf2f(xw[(size_t)s3 * F + f]);
    }
    for (; e < end; e++) {
        int s = col[e];
        s = ((unsigned)s < (unsigned)nN) ? s : 0;
        a0 += dinv[s] * bf2f(xw[(size_t)s * F + f]);
    }
    float acc = dinv[i] * ((a0 + a1) + (a2 + a3)) + bias[f];

    if (stage_conv) stage_conv[(size_t)i * stage_ldo + f] = f2bf(acc);
    int f32m = final_base ? flag[1] : 0;
    if (final_base) {
        size_t conv_idx = (size_t)gridDim.x * 4 + (size_t)i * F + f;
        if (f32m) ((float*)final_base)[conv_idx] = acc;
        else      ((u16*)final_base)[conv_idx] = f2bf(acc);
    }
    if (!out_h) return;

    // LayerNorm over F
    float p1 = acc, p2 = acc * acc;
    #pragma unroll
    for (int o = 32; o >= 1; o >>= 1) {
        p1 += __shfl_down(p1, o);
        p2 += __shfl_down(p2, o);
    }
    __shared__ float red1[8], red2[8], stats[2];
    int lane = threadIdx.x & 63, w = threadIdx.x >> 6;
    if (lane == 0) { red1[w] = p1; red2[w] = p2; }
    __syncthreads();
    if (threadIdx.x == 0) {
        float t1 = 0.f, t2 = 0.f;
        int nw = blockDim.x >> 6;
        for (int j = 0; j < nw; j++) { t1 += red1[j]; t2 += red2[j]; }
        float invF = 1.0f / (float)F;
        float mu = t1 * invF;
        float var = fmaxf(t2 * invF - mu * mu, 0.f);
        stats[0] = mu;
        stats[1] = rsqrtf(var + 1e-5f);
    }
    __syncthreads();
    float y = (acc - stats[0]) * stats[1] * gamma[f] + beta[f];
    if (final_base) {
        size_t bn_idx = (size_t)gridDim.x * (4 + 128) + (size_t)i * F + f;
        if (f32m) ((float*)final_base)[bn_idx] = y;
        else      ((u16*)final_base)[bn_idx] = f2bf(y);
    }
    float h = (y > 0.f) ? y : expm1f(y);
    if (resid) h += bf2f(resid[(size_t)i * F + f]);
    out_h[(size_t)i * F + f] = f2bf(h);
}

// ---------------- standalone LayerNorm + ELU in place (layer 2, F=512) ----------------
__global__ void ln_elu_k(u16* __restrict__ h, const float* __restrict__ gamma,
                         const float* __restrict__ beta, int F) {
    int i = blockIdx.x;
    int f = threadIdx.x;
    size_t idx = (size_t)i * F + f;
    float v = bf2f(h[idx]);
    float p1 = v, p2 = v * v;
    #pragma unroll
    for (int o = 32; o >= 1; o >>= 1) {
        p1 += __shfl_down(p1, o);
        p2 += __shfl_down(p2, o);
    }
    __shared__ float red1[8], red2[8], stats[2];
    int lane = threadIdx.x & 63, w = threadIdx.x >> 6;
    if (lane == 0) { red1[w] = p1; red2[w] = p2; }
    __syncthreads();
    if (threadIdx.x == 0) {
        float t1 = 0.f, t2 = 0.f;
        int nw = blockDim.x >> 6;
        for (int j = 0; j < nw; j++) { t1 += red1[j]; t2 += red2[j]; }
        float invF = 1.0f / (float)F;
        float mu = t1 * invF;
        float var = fmaxf(t2 * invF - mu * mu, 0.f);
        stats[0] = mu;
        stats[1] = rsqrtf(var + 1e-5f);
    }
    __syncthreads();
    float y = (v - stats[0]) * stats[1] * gamma[f] + beta[f];
    float hh = (y > 0.f) ? y : expm1f(y);
    h[idx] = f2bf(hh);
}

// ---------------- classifier ----------------
__global__ void classifier_k(const u16* __restrict__ h, const float* __restrict__ Wcf,
                             const float* __restrict__ bcf, void* __restrict__ out,
                             const int* __restrict__ flag, int n) {
    int gid = blockIdx.x * blockDim.x + threadIdx.x;
    if (gid >= n * 4) return;
    int node = gid >> 2, c = gid & 3;
    float s = bcf[c];
    const u16* hr = h + (size_t)node * 128;
    #pragma unroll 8
    for (int k = 0; k < 128; k++)
        s += bf2f(hr[k]) * Wcf[k * 4 + c];
    if (flag[1]) ((float*)out)[gid] = s;
    else         ((u16*)out)[gid] = f2bf(s);
}

// ---------------- ws-too-small marker ----------------
__global__ void marker_k(float* out) {
    if (threadIdx.x == 0 && blockIdx.x == 0) {
        out[0] = 31337.0f; out[1] = 31337.0f;
    }
}

extern "C" void kernel_launch(void* const* d_in, const int* in_sizes, int n_in,
                              void* d_out, int out_size, void* d_ws, size_t ws_size,
                              hipStream_t stream) {
    const int N = in_sizes[0] / 512;   // 50000
    const int E = in_sizes[1] / 2;     // 1600000

    const void* x  = d_in[0];
    const int* ei  = (const int*)d_in[1];

    // ---- workspace carve ----
    char* p = (char*)d_ws;
    auto alloc = [&](size_t bytes) -> void* {
        void* r = (void*)p;
        p += (bytes + 255) & ~(size_t)255;
        return r;
    };
    int*   flag   = (int*)alloc(256);
    int*   counts = (int*)alloc((size_t)N * 4);
    int*   rowptr = (int*)alloc((size_t)(N + 1) * 4);
    int*   cursor = (int*)alloc((size_t)N * 4);
    int*   incl   = (int*)alloc((size_t)N * 4);
    int*   bsum   = (int*)alloc(256 * 4);
    int*   bscan  = (int*)alloc(256 * 4);
    float* dinv   = (float*)alloc((size_t)N * 4);
    int*   col    = (int*)alloc((size_t)(E + N) * 4);
    float* pbuf   = (float*)alloc(4096 * 4);
    u16* W1t = (u16*)alloc((size_t)512 * 256 * 2);
    u16* W2t = (u16*)alloc((size_t)256 * 512 * 2);
    u16* W3t = (u16*)alloc((size_t)512 * 256 * 2);
    u16* W4t = (u16*)alloc((size_t)256 * 128 * 2);
    u16* bigA = (u16*)alloc((size_t)N * 512 * 2);  // xbf -> h2 -> h4h
    u16* xw   = (u16*)alloc((size_t)N * 256 * 2);  // GEMM scratch
    u16* h1   = (u16*)alloc((size_t)N * 256 * 2);  // layer-1/3 activation

    size_t needed = (size_t)(p - (char*)d_ws);
    if (needed > ws_size) {
        marker_k<<<1, 64, 0, stream>>>((float*)d_out);
        return;
    }

    u16* xbf = bigA;
    u16* h2  = bigA;          // [N,512], alive after xbf dead
    u16* h4h = bigA;          // [N,128], alive after h2 dead

    // param staging offsets in pbuf (floats)
    // b1:0(256) g1:256(256) be1:512(256) b2:768(512) g2:1280(512) be2:1792(512)
    // b3:2304(256) g3:2560(256) be3:2816(256) b4:3072(128) g4:3200(128) be4:3328(128)
    // Wc:3456(512) bc:3968(4)
    PTab tab;
    tab.e[0]  = { d_in[3],  256, 0    };  // b1
    tab.e[1]  = { d_in[12], 256, 256  };  // g1
    tab.e[2]  = { d_in[13], 256, 512  };  // be1
    tab.e[3]  = { d_in[5],  512, 768  };  // b2
    tab.e[4]  = { d_in[14], 512, 1280 };  // g2
    tab.e[5]  = { d_in[15], 512, 1792 };  // be2
    tab.e[6]  = { d_in[7],  256, 2304 };  // b3
    tab.e[7]  = { d_in[16], 256, 2560 };  // g3
    tab.e[8]  = { d_in[17], 256, 2816 };  // be3
    tab.e[9]  = { d_in[9],  128, 3072 };  // b4
    tab.e[10] = { d_in[18], 128, 3200 };  // g4
    tab.e[11] = { d_in[19], 128, 3328 };  // be4
    tab.e[12] = { d_in[10], 512, 3456 };  // Wc
    tab.e[13] = { d_in[11], 4,   3968 };  // bc
    float* b1f = pbuf + 0,   *g1f = pbuf + 256,  *be1f = pbuf + 512;
    float* b2f = pbuf + 768, *g2f = pbuf + 1280, *be2f = pbuf + 1792;
    float* b3f = pbuf + 2304,*g3f = pbuf + 2560, *be3f = pbuf + 2816;
    float* b4f = pbuf + 3072,*g4f = pbuf + 3200, *be4f = pbuf + 3328;
    float* Wcf = pbuf + 3456,*bcf = pbuf + 3968;

    int nb1 = (N + 255) / 256;
    int NB = (N + SCAN_B - 1) / SCAN_B;

    // ---- dtype probes ----
    detect_k<<<1, 256, 0, stream>>>(ei, E, (const u16*)x, flag);

    // ---- canonicalize ----
    cvt_x_k<<<8192, 256, 0, stream>>>(x, xbf, (long)N * 512, flag);
    cvt_wt_k<<<(512 * 256 + 255) / 256, 256, 0, stream>>>(d_in[2], W1t, 512, 256, flag);
    cvt_wt_k<<<(256 * 512 + 255) / 256, 256, 0, stream>>>(d_in[4], W2t, 256, 512, flag);
    cvt_wt_k<<<(512 * 256 + 255) / 256, 256, 0, stream>>>(d_in[6], W3t, 512, 256, flag);
    cvt_wt_k<<<(256 * 128 + 255) / 256, 256, 0, stream>>>(d_in[8], W4t, 256, 128, flag);
    cvt_params_k<<<14, 256, 0, stream>>>(tab, pbuf, flag);

    // ---- CSR build ----
    init_counts_k<<<nb1, 256, 0, stream>>>(counts, N);
    count_edges_k<<<(E + 255) / 256, 256, 0, stream>>>(ei, flag, counts, E, N);
    dinv_k<<<nb1, 256, 0, stream>>>(counts, dinv, N);
    scan1_k<<<NB, SCAN_B, 0, stream>>>(counts, incl, bsum, N);
    scan2_k<<<1, SCAN_B, 0, stream>>>(bsum, bscan, NB);
    rowptr_k<<<NB, SCAN_B, 0, stream>>>(incl, bscan, rowptr, N);
    cursor_k<<<nb1, 256, 0, stream>>>(rowptr, cursor, N);
    scatter_k<<<(E + N + 255) / 256, 256, 0, stream>>>(ei, flag, cursor, col, E, N);

    int gx = (N + TM - 1) / TM;

    // ---- layer 1: xbf[N,512] @ W1 -> agg+LN+ELU -> h1[N,256] ----
    gemm_bt_k<<<dim3(gx, 256 / TN), 256, 0, stream>>>(xbf, W1t, xw, N, 512, 256);
    agg_ln_elu_k<<<N, 256, 0, stream>>>(xw, rowptr, col, dinv, b1f, g1f, be1f,
                                        h1, nullptr, nullptr, 0, nullptr, flag, 256, N);
    // ---- layer 2 (two 256-col halves into h2[N,512]) ----
    gemm_bt_k<<<dim3(gx, 256 / TN), 256, 0, stream>>>(h1, W2t, xw, N, 256, 256);
    agg_ln_elu_k<<<N, 256, 0, stream>>>(xw, rowptr, col, dinv, b2f, nullptr, nullptr,
                                        nullptr, nullptr, h2, 512, nullptr, flag, 256, N);
    gemm_bt_k<<<dim3(gx, 256 / TN), 256, 0, stream>>>(h1, W2t + (size_t)256 * 256, xw, N, 256, 256);
    agg_ln_elu_k<<<N, 256, 0, stream>>>(xw, rowptr, col, dinv, b2f + 256, nullptr, nullptr,
                                        nullptr, nullptr, h2 + 256, 512, nullptr, flag, 256, N);
    ln_elu_k<<<N, 512, 0, stream>>>(h2, g2f, be2f, 512);
    // ---- layer 3: h2[N,512] @ W3 -> agg+LN+ELU + h1 -> h1[N,256] ----
    gemm_bt_k<<<dim3(gx, 256 / TN), 256, 0, stream>>>(h2, W3t, xw, N, 512, 256);
    agg_ln_elu_k<<<N, 256, 0, stream>>>(xw, rowptr, col, dinv, b3f, g3f, be3f,
                                        h1, h1, nullptr, 0, nullptr, flag, 256, N);
    // ---- layer 4: h1[N,256] @ W4 -> agg -> out_conv/out_bn + h4h[N,128] ----
    gemm_bt_k<<<dim3(gx, 128 / TN), 256, 0, stream>>>(h1, W4t, xw, N, 256, 128);
    agg_ln_elu_k<<<N, 128, 0, stream>>>(xw, rowptr, col, dinv, b4f, g4f, be4f,
                                        h4h, nullptr, nullptr, 0, d_out, flag, 128, N);
    // ---- classifier ----
    classifier_k<<<(N * 4 + 255) / 256, 256, 0, stream>>>(h4h, Wcf, bcf, d_out, flag, N);
}

// Round 4
// 1157.262 us; speedup vs baseline: 1.3447x; 1.3447x over previous
//
#include <hip/hip_runtime.h>
#include <hip/hip_bf16.h>
#include <math.h>

typedef unsigned short u16;
typedef u16 us8 __attribute__((ext_vector_type(8)));
typedef __bf16 bf8 __attribute__((ext_vector_type(8)));
typedef float f32x4 __attribute__((ext_vector_type(4)));
typedef float f32x8 __attribute__((ext_vector_type(8)));

#define SCAN_B 256

__device__ __forceinline__ float bf2f(u16 v) {
    unsigned u = ((unsigned)v) << 16;
    return __builtin_bit_cast(float, u);
}
__device__ __forceinline__ u16 f2bf(float f) {
    unsigned u = __builtin_bit_cast(unsigned, f);
    unsigned lsb = (u >> 16) & 1;
    u += 0x7fff + lsb;
    return (u16)(u >> 16);
}
__device__ __forceinline__ void fma8(f32x8& acc, float w, us8 v) {
#pragma unroll
    for (int j = 0; j < 8; j++) acc[j] += w * bf2f(v[j]);
}

// ---------------- runtime dtype probes ----------------
__global__ void detect_k(const int* __restrict__ ei, int E,
                         const u16* __restrict__ xraw, int* flag) {
    __shared__ int c_i32, c_f32;
    if (threadIdx.x == 0) { c_i32 = 0; c_f32 = 0; }
    __syncthreads();
    int ne = (E < 4096) ? E : 4096;
    for (int e = threadIdx.x; e < ne; e += blockDim.x)
        if (ei[2 * e + 1] != 0) c_i32 = 1;
    for (int k = threadIdx.x; k < 8192; k += blockDim.x) {
        u16 v = xraw[2 * k];
        int ex = (v >> 7) & 0xFF;
        if (ex >= 0xF0) atomicAdd(&c_f32, 1);
    }
    __syncthreads();
    if (threadIdx.x == 0) {
        flag[0] = (c_i32 == 0) ? 1 : 0;
        flag[1] = (c_f32 >= 4) ? 1 : 0;
    }
}

// ---------------- canonicalize inputs ----------------
__global__ void cvt_x_k(const void* __restrict__ src, u16* __restrict__ dst,
                        long n, const int* __restrict__ flag) {
    int f32m = flag[1];
    long i0 = (long)blockIdx.x * blockDim.x + threadIdx.x;
    long stride = (long)gridDim.x * blockDim.x;
    if (f32m) {
        const float* s = (const float*)src;
        for (long i = i0; i < n; i += stride) dst[i] = f2bf(s[i]);
    } else {
        const u16* s = (const u16*)src;
        for (long i = i0; i < n; i += stride) dst[i] = s[i];
    }
}

__global__ void cvt_wt_k(const void* __restrict__ W, u16* __restrict__ Wt,
                         int K, int Nn, const int* __restrict__ flag) {
    int t = blockIdx.x * blockDim.x + threadIdx.x;
    if (t >= K * Nn) return;
    int k = t / Nn, nn = t - k * Nn;
    u16 b;
    if (flag[1]) b = f2bf(((const float*)W)[t]);
    else         b = ((const u16*)W)[t];
    Wt[nn * K + k] = b;
}

struct PEnt { const void* s; int n; int off; };
struct PTab { PEnt e[14]; };
__global__ void cvt_params_k(PTab tab, float* __restrict__ pbuf,
                             const int* __restrict__ flag) {
    PEnt en = tab.e[blockIdx.x];
    int f32m = flag[1];
    for (int i = threadIdx.x; i < en.n; i += blockDim.x) {
        float v = f32m ? ((const float*)en.s)[i] : bf2f(((const u16*)en.s)[i]);
        pbuf[en.off + i] = v;
    }
}

// ---------------- CSR build ----------------
__global__ void init_counts_k(int* counts, int n) {
    int i = blockIdx.x * blockDim.x + threadIdx.x;
    if (i < n) counts[i] = 1;
}

__global__ void count_edges_k(const int* __restrict__ ei, const int* __restrict__ flag,
                              int* counts, int E, int n) {
    int e = blockIdx.x * blockDim.x + threadIdx.x;
    if (e >= E) return;
    int d;
    if (flag[0]) d = (int)((const long long*)ei)[(size_t)E + e];
    else         d = ei[(size_t)E + e];
    if ((unsigned)d < (unsigned)n) atomicAdd(&counts[d], 1);
}

__global__ void dinv_k(const int* __restrict__ counts, float* dinv, int n) {
    int i = blockIdx.x * blockDim.x + threadIdx.x;
    if (i < n) dinv[i] = rsqrtf((float)counts[i]);
}

__global__ void scan1_k(const int* __restrict__ counts, int* incl, int* bsum, int n) {
    __shared__ int tmp[SCAN_B];
    int t = threadIdx.x;
    int i = blockIdx.x * SCAN_B + t;
    int v = (i < n) ? counts[i] : 0;
    tmp[t] = v;
    __syncthreads();
    for (int o = 1; o < SCAN_B; o <<= 1) {
        int x = 0;
        if (t >= o) x = tmp[t - o];
        __syncthreads();
        if (t >= o) tmp[t] += x;
        __syncthreads();
    }
    if (i < n) incl[i] = tmp[t];
    if (t == SCAN_B - 1) bsum[blockIdx.x] = tmp[t];
}

__global__ void scan2_k(const int* __restrict__ bsum, int* bscan, int nb) {
    __shared__ int tmp[SCAN_B];
    int t = threadIdx.x;
    tmp[t] = (t < nb) ? bsum[t] : 0;
    __syncthreads();
    for (int o = 1; o < SCAN_B; o <<= 1) {
        int x = 0;
        if (t >= o) x = tmp[t - o];
        __syncthreads();
        if (t >= o) tmp[t] += x;
        __syncthreads();
    }
    bscan[t] = tmp[t];
}

__global__ void rowptr_k(const int* __restrict__ incl, const int* __restrict__ bscan,
                         int* rowptr, int n) {
    int i = blockIdx.x * blockDim.x + threadIdx.x;
    if (i < n) {
        int boff = (blockIdx.x > 0) ? bscan[blockIdx.x - 1] : 0;
        rowptr[i + 1] = incl[i] + boff;
        if (i == 0) rowptr[0] = 0;
    }
}

__global__ void cursor_k(const int* __restrict__ rowptr, int* cursor, int n) {
    int i = blockIdx.x * blockDim.x + threadIdx.x;
    if (i < n) cursor[i] = rowptr[i];
}

__global__ void scatter_k(const int* __restrict__ ei, const int* __restrict__ flag,
                          int* cursor, int* col, int E, int n) {
    int e = blockIdx.x * blockDim.x + threadIdx.x;
    if (e < E) {
        int s, d;
        if (flag[0]) {
            const long long* e64 = (const long long*)ei;
            s = (int)e64[e]; d = (int)e64[(size_t)E + e];
        } else {
            s = ei[e]; d = ei[(size_t)E + e];
        }
        if ((unsigned)s < (unsigned)n && (unsigned)d < (unsigned)n) {
            int pos = atomicAdd(&cursor[d], 1);
            col[pos] = s;
        }
    } else if (e < E + n) {
        int i = e - E;
        int pos = atomicAdd(&cursor[i], 1);
        col[pos] = i;
    }
}

// ---------------- bf16 MFMA GEMM: C[M,Nn] = A[M,K] * Bt[Nn,K]^T ----------------
#define TM 64
#define TN 64
#define BK 32
#define LDSS 40

__global__ __launch_bounds__(256) void gemm_bt_k(
    const u16* __restrict__ A, const u16* __restrict__ Bt,
    u16* __restrict__ C, int M, int K, int Nn) {
    __shared__ u16 As[TM * LDSS];
    __shared__ u16 Bs[TN * LDSS];
    int tid = threadIdx.x;
    int wave = tid >> 6;
    int lane = tid & 63;
    int wm = (wave & 1) * 32;
    int wn = (wave >> 1) * 32;
    int row0 = blockIdx.x * TM;
    int col0 = blockIdx.y * TN;

    f32x4 acc00 = {0.f, 0.f, 0.f, 0.f}, acc01 = acc00, acc10 = acc00, acc11 = acc00;

    int lrow = tid >> 2;
    int lcol = (tid & 3) * 8;
    int q = lane >> 4;
    int m = lane & 15;

    for (int k0 = 0; k0 < K; k0 += BK) {
        int gr = row0 + lrow;
        us8 va = (us8)0;
        if (gr < M) va = *(const us8*)(A + (size_t)gr * K + k0 + lcol);
        *(us8*)(&As[lrow * LDSS + lcol]) = va;
        int gc = col0 + lrow;
        us8 vb = (us8)0;
        if (gc < Nn) vb = *(const us8*)(Bt + (size_t)gc * K + k0 + lcol);
        *(us8*)(&Bs[lrow * LDSS + lcol]) = vb;
        __syncthreads();

        us8 a0 = *(const us8*)(&As[(wm + m) * LDSS + q * 8]);
        us8 a1 = *(const us8*)(&As[(wm + 16 + m) * LDSS + q * 8]);
        us8 b0 = *(const us8*)(&Bs[(wn + m) * LDSS + q * 8]);
        us8 b1 = *(const us8*)(&Bs[(wn + 16 + m) * LDSS + q * 8]);
        bf8 fa0 = __builtin_bit_cast(bf8, a0);
        bf8 fa1 = __builtin_bit_cast(bf8, a1);
        bf8 fb0 = __builtin_bit_cast(bf8, b0);
        bf8 fb1 = __builtin_bit_cast(bf8, b1);
        acc00 = __builtin_amdgcn_mfma_f32_16x16x32_bf16(fa0, fb0, acc00, 0, 0, 0);
        acc01 = __builtin_amdgcn_mfma_f32_16x16x32_bf16(fa0, fb1, acc01, 0, 0, 0);
        acc10 = __builtin_amdgcn_mfma_f32_16x16x32_bf16(fa1, fb0, acc10, 0, 0, 0);
        acc11 = __builtin_amdgcn_mfma_f32_16x16x32_bf16(fa1, fb1, acc11, 0, 0, 0);
        __syncthreads();
    }

    int cn = lane & 15;
    // C/D layout: col = lane&15, row = (lane>>4)*4 + r  [measured m89]
    #pragma unroll
    for (int r = 0; r < 4; r++) {
        int rr = q * 4 + r;
        int row_a = row0 + wm + rr;
        int row_b = row0 + wm + 16 + rr;
        if (row_a < M) {
            C[(size_t)row_a * Nn + col0 + wn + cn] = f2bf(acc00[r]);
            C[(size_t)row_a * Nn + col0 + wn + 16 + cn] = f2bf(acc01[r]);
        }
        if (row_b < M) {
            C[(size_t)row_b * Nn + col0 + wn + cn] = f2bf(acc10[r]);
            C[(size_t)row_b * Nn + col0 + wn + 16 + cn] = f2bf(acc11[r]);
        }
    }
}

// ---------------- vectorized aggregate [+ bias + LN + ELU (+resid) (+classifier)] ------
// grid = N nodes, blockDim = 256. F in {128, 256}, multiple of 8, F <= 256.
// Gather phase: rowt = F/8 lanes cooperatively read one 16B-per-lane row;
// G = 256/rowt edge groups run concurrently -> 16B loads, 4+ rows in flight/wave.
// bias == nullptr  => plain normalized aggregate -> out_h (bf16), no LN/ELU.
// Wcf != nullptr   => fused classifier (layer 4): logits -> final_base.
__global__ __launch_bounds__(256) void agg_k(
    const u16* __restrict__ in, const int* __restrict__ rowptr,
    const int* __restrict__ col, const float* __restrict__ dinv,
    const float* __restrict__ bias, const float* __restrict__ gamma,
    const float* __restrict__ beta, u16* __restrict__ out_h,
    const u16* __restrict__ resid, void* __restrict__ final_base,
    const int* __restrict__ flag, const float* __restrict__ Wcf,
    const float* __restrict__ bcf, int F, int nN) {
    int i = blockIdx.x;
    int tid = threadIdx.x;
    int rowt = F >> 3;                    // lanes per row (32 for F=256, 16 for F=128)
    int lsh = __builtin_ctz(rowt);
    int g = tid >> lsh;                   // edge group
    int G = 256 >> lsh;                   // number of groups
    int f0 = (tid & (rowt - 1)) << 3;     // starting feature for this lane

    int beg = rowptr[i], end = rowptr[i + 1];
    f32x8 acc = {0,0,0,0,0,0,0,0}, acc2 = acc;
    int e = beg + g;
    for (; e + G < end; e += 2 * G) {
        int s0 = col[e], s1 = col[e + G];
        s0 = ((unsigned)s0 < (unsigned)nN) ? s0 : 0;
        s1 = ((unsigned)s1 < (unsigned)nN) ? s1 : 0;
        float w0 = dinv[s0], w1 = dinv[s1];
        us8 v0 = *(const us8*)(in + (size_t)s0 * F + f0);
        us8 v1 = *(const us8*)(in + (size_t)s1 * F + f0);
        fma8(acc, w0, v0);
        fma8(acc2, w1, v1);
    }
    if (e < end) {
        int s = col[e];
        s = ((unsigned)s < (unsigned)nN) ? s : 0;
        us8 v = *(const us8*)(in + (size_t)s * F + f0);
        fma8(acc, dinv[s], v);
    }
    #pragma unroll
    for (int j = 0; j < 8; j++) acc[j] += acc2[j];

    __shared__ float red[2048];   // G*F == 2048 floats always
    #pragma unroll
    for (int j = 0; j < 8; j++) red[g * F + f0 + j] = acc[j];
    __syncthreads();

    float a = 0.f;
    if (tid < F) {
        for (int g2 = 0; g2 < G; g2++) a += red[g2 * F + tid];
    }

    if (!bias) {  // plain mode (layer-2 pre-aggregate)
        if (tid < F) out_h[(size_t)i * F + tid] = f2bf(dinv[i] * a);
        return;
    }

    float accv = 0.f;
    if (tid < F) accv = dinv[i] * a + bias[tid];
    int f32m = final_base ? flag[1] : 0;
    if (final_base && tid < F) {
        size_t conv_idx = (size_t)gridDim.x * 4 + (size_t)i * F + tid;
        if (f32m) ((float*)final_base)[conv_idx] = accv;
        else      ((u16*)final_base)[conv_idx] = f2bf(accv);
    }

    // LayerNorm over F (lanes >= F contribute 0)
    float p1 = accv, p2 = accv * accv;
    #pragma unroll
    for (int o = 32; o >= 1; o >>= 1) {
        p1 += __shfl_down(p1, o);
        p2 += __shfl_down(p2, o);
    }
    __shared__ float red1[4], red2[4], stats[2];
    int lane = tid & 63, w = tid >> 6;
    if (lane == 0) { red1[w] = p1; red2[w] = p2; }
    __syncthreads();
    if (tid == 0) {
        float t1 = 0.f, t2 = 0.f;
        for (int j = 0; j < 4; j++) { t1 += red1[j]; t2 += red2[j]; }
        float invF = 1.0f / (float)F;
        float mu = t1 * invF;
        float var = fmaxf(t2 * invF - mu * mu, 0.f);
        stats[0] = mu;
        stats[1] = rsqrtf(var + 1e-5f);
    }
    __syncthreads();

    float h = 0.f;
    if (tid < F) {
        float y = (accv - stats[0]) * stats[1] * gamma[tid] + beta[tid];
        if (final_base) {
            size_t bn_idx = (size_t)gridDim.x * 4 + (size_t)gridDim.x * F + (size_t)i * F + tid;
            if (f32m) ((float*)final_base)[bn_idx] = y;
            else      ((u16*)final_base)[bn_idx] = f2bf(y);
        }
        h = (y > 0.f) ? y : expm1f(y);
        if (resid) h += bf2f(resid[(size_t)i * F + tid]);
        if (out_h) out_h[(size_t)i * F + tid] = f2bf(h);
    }

    if (Wcf) {  // fused classifier: logits[i][c] = bc[c] + sum_k h[k]*Wc[k][c]
        __syncthreads();
        if (tid < F) red[tid] = h;
        __syncthreads();
        if (tid < 4) {
            float s = bcf[tid];
            for (int k = 0; k < F; k++) s += red[k] * Wcf[k * 4 + tid];
            size_t lidx = (size_t)i * 4 + tid;
            if (f32m) ((float*)final_base)[lidx] = s;
            else      ((u16*)final_base)[lidx] = f2bf(s);
        }
    }
}

// ---------------- standalone bias + LayerNorm + ELU in place (layer 2, F=512) ----------
__global__ void ln_elu_k(u16* __restrict__ h, const float* __restrict__ bias,
                         const float* __restrict__ gamma,
                         const float* __restrict__ beta, int F) {
    int i = blockIdx.x;
    int f = threadIdx.x;
    size_t idx = (size_t)i * F + f;
    float v = bf2f(h[idx]) + (bias ? bias[f] : 0.f);
    float p1 = v, p2 = v * v;
    #pragma unroll
    for (int o = 32; o >= 1; o >>= 1) {
        p1 += __shfl_down(p1, o);
        p2 += __shfl_down(p2, o);
    }
    __shared__ float red1[8], red2[8], stats[2];
    int lane = threadIdx.x & 63, w = threadIdx.x >> 6;
    if (lane == 0) { red1[w] = p1; red2[w] = p2; }
    __syncthreads();
    if (threadIdx.x == 0) {
        float t1 = 0.f, t2 = 0.f;
        int nw = blockDim.x >> 6;
        for (int j = 0; j < nw; j++) { t1 += red1[j]; t2 += red2[j]; }
        float invF = 1.0f / (float)F;
        float mu = t1 * invF;
        float var = fmaxf(t2 * invF - mu * mu, 0.f);
        stats[0] = mu;
        stats[1] = rsqrtf(var + 1e-5f);
    }
    __syncthreads();
    float y = (v - stats[0]) * stats[1] * gamma[f] + beta[f];
    float hh = (y > 0.f) ? y : expm1f(y);
    h[idx] = f2bf(hh);
}

// ---------------- ws-too-small marker ----------------
__global__ void marker_k(float* out) {
    if (threadIdx.x == 0 && blockIdx.x == 0) {
        out[0] = 31337.0f; out[1] = 31337.0f;
    }
}

extern "C" void kernel_launch(void* const* d_in, const int* in_sizes, int n_in,
                              void* d_out, int out_size, void* d_ws, size_t ws_size,
                              hipStream_t stream) {
    const int N = in_sizes[0] / 512;   // 50000
    const int E = in_sizes[1] / 2;     // 1600000

    const void* x  = d_in[0];
    const int* ei  = (const int*)d_in[1];

    // ---- workspace carve ----
    char* p = (char*)d_ws;
    auto alloc = [&](size_t bytes) -> void* {
        void* r = (void*)p;
        p += (bytes + 255) & ~(size_t)255;
        return r;
    };
    int*   flag   = (int*)alloc(256);
    int*   counts = (int*)alloc((size_t)N * 4);
    int*   rowptr = (int*)alloc((size_t)(N + 1) * 4);
    int*   cursor = (int*)alloc((size_t)N * 4);
    int*   incl   = (int*)alloc((size_t)N * 4);
    int*   bsum   = (int*)alloc(256 * 4);
    int*   bscan  = (int*)alloc(256 * 4);
    float* dinv   = (float*)alloc((size_t)N * 4);
    int*   col    = (int*)alloc((size_t)(E + N) * 4);
    float* pbuf   = (float*)alloc(4096 * 4);
    u16* W1t = (u16*)alloc((size_t)512 * 256 * 2);
    u16* W2t = (u16*)alloc((size_t)256 * 512 * 2);
    u16* W3t = (u16*)alloc((size_t)512 * 256 * 2);
    u16* W4t = (u16*)alloc((size_t)256 * 128 * 2);
    u16* bigA = (u16*)alloc((size_t)N * 512 * 2);  // xbf -> h2
    u16* xw   = (u16*)alloc((size_t)N * 256 * 2);  // GEMM scratch / layer-2 pre-agg
    u16* h1   = (u16*)alloc((size_t)N * 256 * 2);  // layer-1/3 activation

    size_t needed = (size_t)(p - (char*)d_ws);
    if (needed > ws_size) {
        marker_k<<<1, 64, 0, stream>>>((float*)d_out);
        return;
    }

    u16* xbf = bigA;
    u16* h2  = bigA;  // [N,512], alive after xbf dead

    PTab tab;
    tab.e[0]  = { d_in[3],  256, 0    };  // b1
    tab.e[1]  = { d_in[12], 256, 256  };  // g1
    tab.e[2]  = { d_in[13], 256, 512  };  // be1
    tab.e[3]  = { d_in[5],  512, 768  };  // b2
    tab.e[4]  = { d_in[14], 512, 1280 };  // g2
    tab.e[5]  = { d_in[15], 512, 1792 };  // be2
    tab.e[6]  = { d_in[7],  256, 2304 };  // b3
    tab.e[7]  = { d_in[16], 256, 2560 };  // g3
    tab.e[8]  = { d_in[17], 256, 2816 };  // be3
    tab.e[9]  = { d_in[9],  128, 3072 };  // b4
    tab.e[10] = { d_in[18], 128, 3200 };  // g4
    tab.e[11] = { d_in[19], 128, 3328 };  // be4
    tab.e[12] = { d_in[10], 512, 3456 };  // Wc
    tab.e[13] = { d_in[11], 4,   3968 };  // bc
    float* b1f = pbuf + 0,   *g1f = pbuf + 256,  *be1f = pbuf + 512;
    float* b2f = pbuf + 768, *g2f = pbuf + 1280, *be2f = pbuf + 1792;
    float* b3f = pbuf + 2304,*g3f = pbuf + 2560, *be3f = pbuf + 2816;
    float* b4f = pbuf + 3072,*g4f = pbuf + 3200, *be4f = pbuf + 3328;
    float* Wcf = pbuf + 3456,*bcf = pbuf + 3968;

    int nb1 = (N + 255) / 256;
    int NB = (N + SCAN_B - 1) / SCAN_B;

    // ---- dtype probes ----
    detect_k<<<1, 256, 0, stream>>>(ei, E, (const u16*)x, flag);

    // ---- canonicalize ----
    cvt_x_k<<<8192, 256, 0, stream>>>(x, xbf, (long)N * 512, flag);
    cvt_wt_k<<<(512 * 256 + 255) / 256, 256, 0, stream>>>(d_in[2], W1t, 512, 256, flag);
    cvt_wt_k<<<(256 * 512 + 255) / 256, 256, 0, stream>>>(d_in[4], W2t, 256, 512, flag);
    cvt_wt_k<<<(512 * 256 + 255) / 256, 256, 0, stream>>>(d_in[6], W3t, 512, 256, flag);
    cvt_wt_k<<<(256 * 128 + 255) / 256, 256, 0, stream>>>(d_in[8], W4t, 256, 128, flag);
    cvt_params_k<<<14, 256, 0, stream>>>(tab, pbuf, flag);

    // ---- CSR build ----
    init_counts_k<<<nb1, 256, 0, stream>>>(counts, N);
    count_edges_k<<<(E + 255) / 256, 256, 0, stream>>>(ei, flag, counts, E, N);
    dinv_k<<<nb1, 256, 0, stream>>>(counts, dinv, N);
    scan1_k<<<NB, SCAN_B, 0, stream>>>(counts, incl, bsum, N);
    scan2_k<<<1, SCAN_B, 0, stream>>>(bsum, bscan, NB);
    rowptr_k<<<NB, SCAN_B, 0, stream>>>(incl, bscan, rowptr, N);
    cursor_k<<<nb1, 256, 0, stream>>>(rowptr, cursor, N);
    scatter_k<<<(E + N + 255) / 256, 256, 0, stream>>>(ei, flag, cursor, col, E, N);

    int gx = (N + TM - 1) / TM;

    // ---- layer 1: xbf[N,512] @ W1 -> agg+LN+ELU -> h1[N,256] ----
    gemm_bt_k<<<dim3(gx, 256 / TN), 256, 0, stream>>>(xbf, W1t, xw, N, 512, 256);
    agg_k<<<N, 256, 0, stream>>>(xw, rowptr, col, dinv, b1f, g1f, be1f,
                                 h1, nullptr, nullptr, flag, nullptr, nullptr, 256, N);
    // ---- layer 2 (agg BEFORE GEMM: agg(h1 @ W2) == agg(h1) @ W2) ----
    agg_k<<<N, 256, 0, stream>>>(h1, rowptr, col, dinv, nullptr, nullptr, nullptr,
                                 xw, nullptr, nullptr, flag, nullptr, nullptr, 256, N);
    gemm_bt_k<<<dim3(gx, 512 / TN), 256, 0, stream>>>(xw, W2t, h2, N, 256, 512);
    ln_elu_k<<<N, 512, 0, stream>>>(h2, b2f, g2f, be2f, 512);
    // ---- layer 3: h2[N,512] @ W3 -> agg+LN+ELU + h1 -> h1[N,256] ----
    gemm_bt_k<<<dim3(gx, 256 / TN), 256, 0, stream>>>(h2, W3t, xw, N, 512, 256);
    agg_k<<<N, 256, 0, stream>>>(xw, rowptr, col, dinv, b3f, g3f, be3f,
                                 h1, h1, nullptr, flag, nullptr, nullptr, 256, N);
    // ---- layer 4: h1[N,256] @ W4 -> agg -> out_conv/out_bn + fused classifier ----
    gemm_bt_k<<<dim3(gx, 128 / TN), 256, 0, stream>>>(h1, W4t, xw, N, 256, 128);
    agg_k<<<N, 256, 0, stream>>>(xw, rowptr, col, dinv, b4f, g4f, be4f,
                                 nullptr, nullptr, d_out, flag, Wcf, bcf, 128, N);
}

// Round 5
// 1045.962 us; speedup vs baseline: 1.4878x; 1.1064x over previous
//
#include <hip/hip_runtime.h>
#include <hip/hip_bf16.h>
#include <math.h>

typedef unsigned short u16;
typedef u16 us8 __attribute__((ext_vector_type(8)));
typedef __bf16 bf8 __attribute__((ext_vector_type(8)));
typedef float f32x4 __attribute__((ext_vector_type(4)));
typedef float f32x8 __attribute__((ext_vector_type(8)));

#define SCAN_B 256

__device__ __forceinline__ float bf2f(u16 v) {
    unsigned u = ((unsigned)v) << 16;
    return __builtin_bit_cast(float, u);
}
__device__ __forceinline__ u16 f2bf(float f) {
    unsigned u = __builtin_bit_cast(unsigned, f);
    unsigned lsb = (u >> 16) & 1;
    u += 0x7fff + lsb;
    return (u16)(u >> 16);
}
__device__ __forceinline__ void fma8(f32x8& acc, float w, us8 v) {
#pragma unroll
    for (int j = 0; j < 8; j++) acc[j] += w * bf2f(v[j]);
}

// ---------------- runtime dtype probes ----------------
__global__ void detect_k(const int* __restrict__ ei, int E,
                         const u16* __restrict__ xraw, int* flag) {
    __shared__ int c_i32, c_f32;
    if (threadIdx.x == 0) { c_i32 = 0; c_f32 = 0; }
    __syncthreads();
    int ne = (E < 4096) ? E : 4096;
    for (int e = threadIdx.x; e < ne; e += blockDim.x)
        if (ei[2 * e + 1] != 0) c_i32 = 1;
    for (int k = threadIdx.x; k < 8192; k += blockDim.x) {
        u16 v = xraw[2 * k];
        int ex = (v >> 7) & 0xFF;
        if (ex >= 0xF0) atomicAdd(&c_f32, 1);
    }
    __syncthreads();
    if (threadIdx.x == 0) {
        flag[0] = (c_i32 == 0) ? 1 : 0;
        flag[1] = (c_f32 >= 4) ? 1 : 0;
    }
}

// ---------------- canonicalize inputs ----------------
__global__ void cvt_x_k(const void* __restrict__ src, u16* __restrict__ dst,
                        long n, const int* __restrict__ flag) {
    int f32m = flag[1];
    long i0 = (long)blockIdx.x * blockDim.x + threadIdx.x;
    long stride = (long)gridDim.x * blockDim.x;
    if (f32m) {
        const float* s = (const float*)src;
        for (long i = i0; i < n; i += stride) dst[i] = f2bf(s[i]);
    } else {
        const u16* s = (const u16*)src;
        for (long i = i0; i < n; i += stride) dst[i] = s[i];
    }
}

__global__ void cvt_wt_k(const void* __restrict__ W, u16* __restrict__ Wt,
                         int K, int Nn, const int* __restrict__ flag) {
    int t = blockIdx.x * blockDim.x + threadIdx.x;
    if (t >= K * Nn) return;
    int k = t / Nn, nn = t - k * Nn;
    u16 b;
    if (flag[1]) b = f2bf(((const float*)W)[t]);
    else         b = ((const u16*)W)[t];
    Wt[nn * K + k] = b;
}

struct PEnt { const void* s; int n; int off; };
struct PTab { PEnt e[14]; };
__global__ void cvt_params_k(PTab tab, float* __restrict__ pbuf,
                             const int* __restrict__ flag) {
    PEnt en = tab.e[blockIdx.x];
    int f32m = flag[1];
    for (int i = threadIdx.x; i < en.n; i += blockDim.x) {
        float v = f32m ? ((const float*)en.s)[i] : bf2f(((const u16*)en.s)[i]);
        pbuf[en.off + i] = v;
    }
}

// ---------------- CSR build ----------------
__global__ void init_counts_k(int* counts, int n) {
    int i = blockIdx.x * blockDim.x + threadIdx.x;
    if (i < n) counts[i] = 1;
}

__global__ void count_edges_k(const int* __restrict__ ei, const int* __restrict__ flag,
                              int* counts, int E, int n) {
    int e = blockIdx.x * blockDim.x + threadIdx.x;
    if (e >= E) return;
    int d;
    if (flag[0]) d = (int)((const long long*)ei)[(size_t)E + e];
    else         d = ei[(size_t)E + e];
    if ((unsigned)d < (unsigned)n) atomicAdd(&counts[d], 1);
}

__global__ void dinv_k(const int* __restrict__ counts, float* dinv, int n) {
    int i = blockIdx.x * blockDim.x + threadIdx.x;
    if (i < n) dinv[i] = rsqrtf((float)counts[i]);
}

__global__ void scan1_k(const int* __restrict__ counts, int* incl, int* bsum, int n) {
    __shared__ int tmp[SCAN_B];
    int t = threadIdx.x;
    int i = blockIdx.x * SCAN_B + t;
    int v = (i < n) ? counts[i] : 0;
    tmp[t] = v;
    __syncthreads();
    for (int o = 1; o < SCAN_B; o <<= 1) {
        int x = 0;
        if (t >= o) x = tmp[t - o];
        __syncthreads();
        if (t >= o) tmp[t] += x;
        __syncthreads();
    }
    if (i < n) incl[i] = tmp[t];
    if (t == SCAN_B - 1) bsum[blockIdx.x] = tmp[t];
}

__global__ void scan2_k(const int* __restrict__ bsum, int* bscan, int nb) {
    __shared__ int tmp[SCAN_B];
    int t = threadIdx.x;
    tmp[t] = (t < nb) ? bsum[t] : 0;
    __syncthreads();
    for (int o = 1; o < SCAN_B; o <<= 1) {
        int x = 0;
        if (t >= o) x = tmp[t - o];
        __syncthreads();
        if (t >= o) tmp[t] += x;
        __syncthreads();
    }
    bscan[t] = tmp[t];
}

__global__ void rowptr_k(const int* __restrict__ incl, const int* __restrict__ bscan,
                         int* rowptr, int n) {
    int i = blockIdx.x * blockDim.x + threadIdx.x;
    if (i < n) {
        int boff = (blockIdx.x > 0) ? bscan[blockIdx.x - 1] : 0;
        rowptr[i + 1] = incl[i] + boff;
        if (i == 0) rowptr[0] = 0;
    }
}

__global__ void cursor_k(const int* __restrict__ rowptr, int* cursor, int n) {
    int i = blockIdx.x * blockDim.x + threadIdx.x;
    if (i < n) cursor[i] = rowptr[i];
}

__global__ void scatter_k(const int* __restrict__ ei, const int* __restrict__ flag,
                          int* cursor, int* col, int E, int n) {
    int e = blockIdx.x * blockDim.x + threadIdx.x;
    if (e < E) {
        int s, d;
        if (flag[0]) {
            const long long* e64 = (const long long*)ei;
            s = (int)e64[e]; d = (int)e64[(size_t)E + e];
        } else {
            s = ei[e]; d = ei[(size_t)E + e];
        }
        if ((unsigned)s < (unsigned)n && (unsigned)d < (unsigned)n) {
            int pos = atomicAdd(&cursor[d], 1);
            col[pos] = s;
        }
    } else if (e < E + n) {
        int i = e - E;
        int pos = atomicAdd(&cursor[i], 1);
        col[pos] = i;
    }
}

// ---------------- bf16 MFMA GEMM: C[M,Nn] = A[M,K] * Bt[Nn,K]^T ----------------
#define TM 64
#define TN 64
#define BK 32
#define LDSS 40

__global__ __launch_bounds__(256) void gemm_bt_k(
    const u16* __restrict__ A, const u16* __restrict__ Bt,
    u16* __restrict__ C, int M, int K, int Nn) {
    __shared__ u16 As[TM * LDSS];
    __shared__ u16 Bs[TN * LDSS];
    int tid = threadIdx.x;
    int wave = tid >> 6;
    int lane = tid & 63;
    int wm = (wave & 1) * 32;
    int wn = (wave >> 1) * 32;
    int row0 = blockIdx.x * TM;
    int col0 = blockIdx.y * TN;

    f32x4 acc00 = {0.f, 0.f, 0.f, 0.f}, acc01 = acc00, acc10 = acc00, acc11 = acc00;

    int lrow = tid >> 2;
    int lcol = (tid & 3) * 8;
    int q = lane >> 4;
    int m = lane & 15;

    for (int k0 = 0; k0 < K; k0 += BK) {
        int gr = row0 + lrow;
        us8 va = (us8)0;
        if (gr < M) va = *(const us8*)(A + (size_t)gr * K + k0 + lcol);
        *(us8*)(&As[lrow * LDSS + lcol]) = va;
        int gc = col0 + lrow;
        us8 vb = (us8)0;
        if (gc < Nn) vb = *(const us8*)(Bt + (size_t)gc * K + k0 + lcol);
        *(us8*)(&Bs[lrow * LDSS + lcol]) = vb;
        __syncthreads();

        us8 a0 = *(const us8*)(&As[(wm + m) * LDSS + q * 8]);
        us8 a1 = *(const us8*)(&As[(wm + 16 + m) * LDSS + q * 8]);
        us8 b0 = *(const us8*)(&Bs[(wn + m) * LDSS + q * 8]);
        us8 b1 = *(const us8*)(&Bs[(wn + 16 + m) * LDSS + q * 8]);
        bf8 fa0 = __builtin_bit_cast(bf8, a0);
        bf8 fa1 = __builtin_bit_cast(bf8, a1);
        bf8 fb0 = __builtin_bit_cast(bf8, b0);
        bf8 fb1 = __builtin_bit_cast(bf8, b1);
        acc00 = __builtin_amdgcn_mfma_f32_16x16x32_bf16(fa0, fb0, acc00, 0, 0, 0);
        acc01 = __builtin_amdgcn_mfma_f32_16x16x32_bf16(fa0, fb1, acc01, 0, 0, 0);
        acc10 = __builtin_amdgcn_mfma_f32_16x16x32_bf16(fa1, fb0, acc10, 0, 0, 0);
        acc11 = __builtin_amdgcn_mfma_f32_16x16x32_bf16(fa1, fb1, acc11, 0, 0, 0);
        __syncthreads();
    }

    int cn = lane & 15;
    // C/D layout: col = lane&15, row = (lane>>4)*4 + r  [measured m89]
    #pragma unroll
    for (int r = 0; r < 4; r++) {
        int rr = q * 4 + r;
        int row_a = row0 + wm + rr;
        int row_b = row0 + wm + 16 + rr;
        if (row_a < M) {
            C[(size_t)row_a * Nn + col0 + wn + cn] = f2bf(acc00[r]);
            C[(size_t)row_a * Nn + col0 + wn + 16 + cn] = f2bf(acc01[r]);
        }
        if (row_b < M) {
            C[(size_t)row_b * Nn + col0 + wn + cn] = f2bf(acc10[r]);
            C[(size_t)row_b * Nn + col0 + wn + 16 + cn] = f2bf(acc11[r]);
        }
    }
}

// ---------------- wave-per-node aggregate [+ bias + LN + ELU (+resid) (+classifier)] ---
// grid = ceil(N/4) blocks x 256 threads = 4 waves; wave w owns node blockIdx*4+w.
// Within a wave: rowt = F/8 lanes per row (16B/lane vector gathers), Gw = 64/rowt edge
// groups. Cross-group combine via shuffles only — NO LDS, NO __syncthreads.
// bias == nullptr => plain normalized aggregate -> out_h. Wcf => fused classifier.
__global__ __launch_bounds__(256) void agg_k(
    const u16* __restrict__ in, const int* __restrict__ rowptr,
    const int* __restrict__ col, const float* __restrict__ dinv,
    const float* __restrict__ bias, const float* __restrict__ gamma,
    const float* __restrict__ beta, u16* __restrict__ out_h,
    const u16* __restrict__ resid, void* __restrict__ final_base,
    const int* __restrict__ flag, const float* __restrict__ Wcf,
    const float* __restrict__ bcf, int F, int nN) {
    int wv = threadIdx.x >> 6;
    int lane = threadIdx.x & 63;
    int i = blockIdx.x * 4 + wv;
    if (i >= nN) return;

    int rowt = F >> 3;                    // 32 (F=256) or 16 (F=128)
    int Gw = 64 / rowt;                   // 2 or 4 edge groups per wave
    int g = lane / rowt;
    int f0 = (lane & (rowt - 1)) << 3;

    int beg = rowptr[i], end = rowptr[i + 1];
    f32x8 acc = {0, 0, 0, 0, 0, 0, 0, 0}, acc2 = acc;
    int e = beg + g;
    for (; e + Gw < end; e += 2 * Gw) {
        int s0 = col[e], s1 = col[e + Gw];
        s0 = ((unsigned)s0 < (unsigned)nN) ? s0 : 0;
        s1 = ((unsigned)s1 < (unsigned)nN) ? s1 : 0;
        float w0 = dinv[s0], w1 = dinv[s1];
        us8 v0 = *(const us8*)(in + (unsigned)(s0 * F) + f0);
        us8 v1 = *(const us8*)(in + (unsigned)(s1 * F) + f0);
        fma8(acc, w0, v0);
        fma8(acc2, w1, v1);
    }
    if (e < end) {
        int s = col[e];
        s = ((unsigned)s < (unsigned)nN) ? s : 0;
        us8 v = *(const us8*)(in + (unsigned)(s * F) + f0);
        fma8(acc, dinv[s], v);
    }
    #pragma unroll
    for (int j = 0; j < 8; j++) acc[j] += acc2[j];

    // cross-group combine via shuffles (lanes < rowt end with the full row slice)
    for (int o = 32; o >= rowt; o >>= 1) {
        #pragma unroll
        for (int j = 0; j < 8; j++) acc[j] += __shfl_down(acc[j], o);
    }
    bool active = lane < rowt;
    float di = dinv[i];

    if (!bias) {  // plain mode (layer-2 pre-aggregate)
        if (active) {
            us8 o8;
            #pragma unroll
            for (int j = 0; j < 8; j++) o8[j] = f2bf(di * acc[j]);
            *(us8*)(out_h + (unsigned)(i * F) + f0) = o8;
        }
        return;
    }

    f32x8 accv = {0, 0, 0, 0, 0, 0, 0, 0};
    if (active) {
        #pragma unroll
        for (int j = 0; j < 8; j++) accv[j] = di * acc[j] + bias[f0 + j];
    }
    int f32m = final_base ? flag[1] : 0;
    if (final_base && active) {
        size_t conv_idx = (size_t)nN * 4 + (size_t)i * F + f0;
        if (f32m) {
            #pragma unroll
            for (int j = 0; j < 8; j++) ((float*)final_base)[conv_idx + j] = accv[j];
        } else {
            us8 o8;
            #pragma unroll
            for (int j = 0; j < 8; j++) o8[j] = f2bf(accv[j]);
            *(us8*)((u16*)final_base + conv_idx) = o8;
        }
    }

    // LayerNorm stats: per-lane 8-element partials, shfl_xor across rowt lanes
    float p1 = 0.f, p2 = 0.f;
    #pragma unroll
    for (int j = 0; j < 8; j++) { p1 += accv[j]; p2 += accv[j] * accv[j]; }
    for (int o = rowt >> 1; o >= 1; o >>= 1) {
        p1 += __shfl_xor(p1, o);
        p2 += __shfl_xor(p2, o);
    }
    float invF = 1.0f / (float)F;
    float mu = p1 * invF;
    float var = fmaxf(p2 * invF - mu * mu, 0.f);
    float rstd = rsqrtf(var + 1e-5f);

    f32x8 h8 = {0, 0, 0, 0, 0, 0, 0, 0};
    if (active) {
        f32x8 y8;
        #pragma unroll
        for (int j = 0; j < 8; j++)
            y8[j] = (accv[j] - mu) * rstd * gamma[f0 + j] + beta[f0 + j];
        if (final_base) {
            size_t bn_idx = (size_t)nN * 4 + (size_t)nN * F + (size_t)i * F + f0;
            if (f32m) {
                #pragma unroll
                for (int j = 0; j < 8; j++) ((float*)final_base)[bn_idx + j] = y8[j];
            } else {
                us8 o8;
                #pragma unroll
                for (int j = 0; j < 8; j++) o8[j] = f2bf(y8[j]);
                *(us8*)((u16*)final_base + bn_idx) = o8;
            }
        }
        #pragma unroll
        for (int j = 0; j < 8; j++) h8[j] = (y8[j] > 0.f) ? y8[j] : expm1f(y8[j]);
        if (resid) {
            us8 r8 = *(const us8*)(resid + (unsigned)(i * F) + f0);
            #pragma unroll
            for (int j = 0; j < 8; j++) h8[j] += bf2f(r8[j]);
        }
        if (out_h) {
            us8 o8;
            #pragma unroll
            for (int j = 0; j < 8; j++) o8[j] = f2bf(h8[j]);
            *(us8*)(out_h + (unsigned)(i * F) + f0) = o8;
        }
    }

    if (Wcf) {  // fused classifier: logits[i][c] = bc[c] + sum_k h[k]*Wc[k][c]
        float s0 = 0.f, s1 = 0.f, s2 = 0.f, s3 = 0.f;
        if (active) {
            #pragma unroll
            for (int j = 0; j < 8; j++) {
                const float* wr = Wcf + (f0 + j) * 4;
                s0 += h8[j] * wr[0];
                s1 += h8[j] * wr[1];
                s2 += h8[j] * wr[2];
                s3 += h8[j] * wr[3];
            }
        }
        for (int o = rowt >> 1; o >= 1; o >>= 1) {
            s0 += __shfl_xor(s0, o);
            s1 += __shfl_xor(s1, o);
            s2 += __shfl_xor(s2, o);
            s3 += __shfl_xor(s3, o);
        }
        if (lane == 0) {
            size_t lidx = (size_t)i * 4;
            if (f32m) {
                ((float*)final_base)[lidx + 0] = s0 + bcf[0];
                ((float*)final_base)[lidx + 1] = s1 + bcf[1];
                ((float*)final_base)[lidx + 2] = s2 + bcf[2];
                ((float*)final_base)[lidx + 3] = s3 + bcf[3];
            } else {
                ((u16*)final_base)[lidx + 0] = f2bf(s0 + bcf[0]);
                ((u16*)final_base)[lidx + 1] = f2bf(s1 + bcf[1]);
                ((u16*)final_base)[lidx + 2] = f2bf(s2 + bcf[2]);
                ((u16*)final_base)[lidx + 3] = f2bf(s3 + bcf[3]);
            }
        }
    }
}

// ---------------- standalone bias + LayerNorm + ELU in place (layer 2, F=512) ----------
__global__ void ln_elu_k(u16* __restrict__ h, const float* __restrict__ bias,
                         const float* __restrict__ gamma,
                         const float* __restrict__ beta, int F) {
    int i = blockIdx.x;
    int f = threadIdx.x;
    size_t idx = (size_t)i * F + f;
    float v = bf2f(h[idx]) + (bias ? bias[f] : 0.f);
    float p1 = v, p2 = v * v;
    #pragma unroll
    for (int o = 32; o >= 1; o >>= 1) {
        p1 += __shfl_down(p1, o);
        p2 += __shfl_down(p2, o);
    }
    __shared__ float red1[8], red2[8], stats[2];
    int lane = threadIdx.x & 63, w = threadIdx.x >> 6;
    if (lane == 0) { red1[w] = p1; red2[w] = p2; }
    __syncthreads();
    if (threadIdx.x == 0) {
        float t1 = 0.f, t2 = 0.f;
        int nw = blockDim.x >> 6;
        for (int j = 0; j < nw; j++) { t1 += red1[j]; t2 += red2[j]; }
        float invF = 1.0f / (float)F;
        float mu = t1 * invF;
        float var = fmaxf(t2 * invF - mu * mu, 0.f);
        stats[0] = mu;
        stats[1] = rsqrtf(var + 1e-5f);
    }
    __syncthreads();
    float y = (v - stats[0]) * stats[1] * gamma[f] + beta[f];
    float hh = (y > 0.f) ? y : expm1f(y);
    h[idx] = f2bf(hh);
}

// ---------------- ws-too-small marker ----------------
__global__ void marker_k(float* out) {
    if (threadIdx.x == 0 && blockIdx.x == 0) {
        out[0] = 31337.0f; out[1] = 31337.0f;
    }
}

extern "C" void kernel_launch(void* const* d_in, const int* in_sizes, int n_in,
                              void* d_out, int out_size, void* d_ws, size_t ws_size,
                              hipStream_t stream) {
    const int N = in_sizes[0] / 512;   // 50000
    const int E = in_sizes[1] / 2;     // 1600000

    const void* x  = d_in[0];
    const int* ei  = (const int*)d_in[1];

    // ---- workspace carve ----
    char* p = (char*)d_ws;
    auto alloc = [&](size_t bytes) -> void* {
        void* r = (void*)p;
        p += (bytes + 255) & ~(size_t)255;
        return r;
    };
    int*   flag   = (int*)alloc(256);
    int*   counts = (int*)alloc((size_t)N * 4);
    int*   rowptr = (int*)alloc((size_t)(N + 1) * 4);
    int*   cursor = (int*)alloc((size_t)N * 4);
    int*   incl   = (int*)alloc((size_t)N * 4);
    int*   bsum   = (int*)alloc(256 * 4);
    int*   bscan  = (int*)alloc(256 * 4);
    float* dinv   = (float*)alloc((size_t)N * 4);
    int*   col    = (int*)alloc((size_t)(E + N) * 4);
    float* pbuf   = (float*)alloc(4096 * 4);
    u16* W1t = (u16*)alloc((size_t)512 * 256 * 2);
    u16* W2t = (u16*)alloc((size_t)256 * 512 * 2);
    u16* W3t = (u16*)alloc((size_t)512 * 256 * 2);
    u16* W4t = (u16*)alloc((size_t)256 * 128 * 2);
    u16* bigA = (u16*)alloc((size_t)N * 512 * 2);  // xbf -> h2
    u16* xw   = (u16*)alloc((size_t)N * 256 * 2);  // GEMM scratch / layer-2 pre-agg
    u16* h1   = (u16*)alloc((size_t)N * 256 * 2);  // layer-1/3 activation

    size_t needed = (size_t)(p - (char*)d_ws);
    if (needed > ws_size) {
        marker_k<<<1, 64, 0, stream>>>((float*)d_out);
        return;
    }

    u16* xbf = bigA;
    u16* h2  = bigA;  // [N,512], alive after xbf dead

    PTab tab;
    tab.e[0]  = { d_in[3],  256, 0    };  // b1
    tab.e[1]  = { d_in[12], 256, 256  };  // g1
    tab.e[2]  = { d_in[13], 256, 512  };  // be1
    tab.e[3]  = { d_in[5],  512, 768  };  // b2
    tab.e[4]  = { d_in[14], 512, 1280 };  // g2
    tab.e[5]  = { d_in[15], 512, 1792 };  // be2
    tab.e[6]  = { d_in[7],  256, 2304 };  // b3
    tab.e[7]  = { d_in[16], 256, 2560 };  // g3
    tab.e[8]  = { d_in[17], 256, 2816 };  // be3
    tab.e[9]  = { d_in[9],  128, 3072 };  // b4
    tab.e[10] = { d_in[18], 128, 3200 };  // g4
    tab.e[11] = { d_in[19], 128, 3328 };  // be4
    tab.e[12] = { d_in[10], 512, 3456 };  // Wc
    tab.e[13] = { d_in[11], 4,   3968 };  // bc
    float* b1f = pbuf + 0,   *g1f = pbuf + 256,  *be1f = pbuf + 512;
    float* b2f = pbuf + 768, *g2f = pbuf + 1280, *be2f = pbuf + 1792;
    float* b3f = pbuf + 2304,*g3f = pbuf + 2560, *be3f = pbuf + 2816;
    float* b4f = pbuf + 3072,*g4f = pbuf + 3200, *be4f = pbuf + 3328;
    float* Wcf = pbuf + 3456,*bcf = pbuf + 3968;

    int nb1 = (N + 255) / 256;
    int NB = (N + SCAN_B - 1) / SCAN_B;

    // ---- dtype probes ----
    detect_k<<<1, 256, 0, stream>>>(ei, E, (const u16*)x, flag);

    // ---- canonicalize ----
    cvt_x_k<<<8192, 256, 0, stream>>>(x, xbf, (long)N * 512, flag);
    cvt_wt_k<<<(512 * 256 + 255) / 256, 256, 0, stream>>>(d_in[2], W1t, 512, 256, flag);
    cvt_wt_k<<<(256 * 512 + 255) / 256, 256, 0, stream>>>(d_in[4], W2t, 256, 512, flag);
    cvt_wt_k<<<(512 * 256 + 255) / 256, 256, 0, stream>>>(d_in[6], W3t, 512, 256, flag);
    cvt_wt_k<<<(256 * 128 + 255) / 256, 256, 0, stream>>>(d_in[8], W4t, 256, 128, flag);
    cvt_params_k<<<14, 256, 0, stream>>>(tab, pbuf, flag);

    // ---- CSR build ----
    init_counts_k<<<nb1, 256, 0, stream>>>(counts, N);
    count_edges_k<<<(E + 255) / 256, 256, 0, stream>>>(ei, flag, counts, E, N);
    dinv_k<<<nb1, 256, 0, stream>>>(counts, dinv, N);
    scan1_k<<<NB, SCAN_B, 0, stream>>>(counts, incl, bsum, N);
    scan2_k<<<1, SCAN_B, 0, stream>>>(bsum, bscan, NB);
    rowptr_k<<<NB, SCAN_B, 0, stream>>>(incl, bscan, rowptr, N);
    cursor_k<<<nb1, 256, 0, stream>>>(rowptr, cursor, N);
    scatter_k<<<(E + N + 255) / 256, 256, 0, stream>>>(ei, flag, cursor, col, E, N);

    int gx = (N + TM - 1) / TM;
    int ga = (N + 3) / 4;

    // ---- layer 1: xbf[N,512] @ W1 -> agg+LN+ELU -> h1[N,256] ----
    gemm_bt_k<<<dim3(gx, 256 / TN), 256, 0, stream>>>(xbf, W1t, xw, N, 512, 256);
    agg_k<<<ga, 256, 0, stream>>>(xw, rowptr, col, dinv, b1f, g1f, be1f,
                                  h1, nullptr, nullptr, flag, nullptr, nullptr, 256, N);
    // ---- layer 2 (agg BEFORE GEMM: agg(h1 @ W2) == agg(h1) @ W2) ----
    agg_k<<<ga, 256, 0, stream>>>(h1, rowptr, col, dinv, nullptr, nullptr, nullptr,
                                  xw, nullptr, nullptr, flag, nullptr, nullptr, 256, N);
    gemm_bt_k<<<dim3(gx, 512 / TN), 256, 0, stream>>>(xw, W2t, h2, N, 256, 512);
    ln_elu_k<<<N, 512, 0, stream>>>(h2, b2f, g2f, be2f, 512);
    // ---- layer 3: h2[N,512] @ W3 -> agg+LN+ELU + h1 -> h1[N,256] ----
    gemm_bt_k<<<dim3(gx, 256 / TN), 256, 0, stream>>>(h2, W3t, xw, N, 512, 256);
    agg_k<<<ga, 256, 0, stream>>>(xw, rowptr, col, dinv, b3f, g3f, be3f,
                                  h1, h1, nullptr, flag, nullptr, nullptr, 256, N);
    // ---- layer 4: h1[N,256] @ W4 -> agg -> out_conv/out_bn + fused classifier ----
    gemm_bt_k<<<dim3(gx, 128 / TN), 256, 0, stream>>>(h1, W4t, xw, N, 256, 128);
    agg_k<<<ga, 256, 0, stream>>>(xw, rowptr, col, dinv, b4f, g4f, be4f,
                                  nullptr, nullptr, d_out, flag, Wcf, bcf, 128, N);
}

// Round 6
// 990.048 us; speedup vs baseline: 1.5718x; 1.0565x over previous
//
#include <hip/hip_runtime.h>
#include <hip/hip_bf16.h>
#include <math.h>

typedef unsigned short u16;
typedef u16 us8 __attribute__((ext_vector_type(8)));
typedef u16 us4 __attribute__((ext_vector_type(4)));
typedef float f32x4 __attribute__((ext_vector_type(4)));
typedef float f32x8 __attribute__((ext_vector_type(8)));
typedef __bf16 bf8 __attribute__((ext_vector_type(8)));

#define SCAN_B 256
#define CH 8192   // edges per bucket-sort block

__device__ __forceinline__ float bf2f(u16 v) {
    unsigned u = ((unsigned)v) << 16;
    return __builtin_bit_cast(float, u);
}
__device__ __forceinline__ u16 f2bf(float f) {
    unsigned u = __builtin_bit_cast(unsigned, f);
    unsigned lsb = (u >> 16) & 1;
    u += 0x7fff + lsb;
    return (u16)(u >> 16);
}
__device__ __forceinline__ void fma8(f32x8& acc, float w, us8 v) {
#pragma unroll
    for (int j = 0; j < 8; j++) acc[j] += w * bf2f(v[j]);
}

// ---------------- runtime dtype probes ----------------
__global__ void detect_k(const int* __restrict__ ei, int E,
                         const u16* __restrict__ xraw, int* flag) {
    __shared__ int c_i32, c_f32;
    if (threadIdx.x == 0) { c_i32 = 0; c_f32 = 0; }
    __syncthreads();
    int ne = (E < 4096) ? E : 4096;
    for (int e = threadIdx.x; e < ne; e += blockDim.x)
        if (ei[2 * e + 1] != 0) c_i32 = 1;
    for (int k = threadIdx.x; k < 8192; k += blockDim.x) {
        u16 v = xraw[2 * k];
        int ex = (v >> 7) & 0xFF;
        if (ex >= 0xF0) atomicAdd(&c_f32, 1);
    }
    __syncthreads();
    if (threadIdx.x == 0) {
        flag[0] = (c_i32 == 0) ? 1 : 0;
        flag[1] = (c_f32 >= 4) ? 1 : 0;
    }
}

// ---------------- canonicalize inputs (vectorized) ----------------
__global__ void cvt_x_k(const void* __restrict__ src, u16* __restrict__ dst,
                        long nq, const int* __restrict__ flag) {  // nq = n/4
    int f32m = flag[1];
    long i0 = (long)blockIdx.x * blockDim.x + threadIdx.x;
    long stride = (long)gridDim.x * blockDim.x;
    if (f32m) {
        const f32x4* s = (const f32x4*)src;
        for (long i = i0; i < nq; i += stride) {
            f32x4 v = s[i];
            us4 o;
            #pragma unroll
            for (int j = 0; j < 4; j++) o[j] = f2bf(v[j]);
            ((us4*)dst)[i] = o;
        }
    } else {
        const us4* s = (const us4*)src;
        for (long i = i0; i < nq; i += stride) ((us4*)dst)[i] = s[i];
    }
}

__global__ void cvt_wt_k(const void* __restrict__ W, u16* __restrict__ Wt,
                         int K, int Nn, const int* __restrict__ flag) {
    int t = blockIdx.x * blockDim.x + threadIdx.x;
    if (t >= K * Nn) return;
    int k = t / Nn, nn = t - k * Nn;
    u16 b;
    if (flag[1]) b = f2bf(((const float*)W)[t]);
    else         b = ((const u16*)W)[t];
    Wt[nn * K + k] = b;
}

struct PEnt { const void* s; int n; int off; };
struct PTab { PEnt e[14]; };
__global__ void cvt_params_k(PTab tab, float* __restrict__ pbuf,
                             const int* __restrict__ flag) {
    PEnt en = tab.e[blockIdx.x];
    int f32m = flag[1];
    for (int i = threadIdx.x; i < en.n; i += blockDim.x) {
        float v = f32m ? ((const float*)en.s)[i] : bf2f(((const u16*)en.s)[i]);
        pbuf[en.off + i] = v;
    }
}

// ---------------- CSR build (bucket-sorted, low write-amplification) ----------------
__global__ void init_counts_k(int* counts, int n) {
    int i = blockIdx.x * blockDim.x + threadIdx.x;
    if (i < n) counts[i] = 1;  // self-loop
}

// Pass A: per-block bucket histogram (bucket = dst >> shiftv)
__global__ void histA_k(const int* __restrict__ ei, const int* __restrict__ flag,
                        int* __restrict__ hist, int E, int n, int NB, int NBUK, int shiftv) {
    __shared__ int lh[256];
    int blk = blockIdx.x;
    for (int b = threadIdx.x; b < NBUK; b += 256) lh[b] = 0;
    __syncthreads();
    int e0 = blk * CH;
    int e1 = min(e0 + CH, E);
    int i64 = flag[0];
    for (int e = e0 + threadIdx.x; e < e1; e += 256) {
        int d;
        if (i64) d = (int)((const long long*)ei)[(size_t)E + e];
        else     d = ei[(size_t)E + e];
        int b = ((unsigned)d < (unsigned)n) ? min(d >> shiftv, NBUK - 1) : (NBUK - 1);
        atomicAdd(&lh[b], 1);
    }
    __syncthreads();
    for (int b = threadIdx.x; b < NBUK; b += 256) hist[b * NB + blk] = lh[b];
}

// generic block-scan (also reused for node-degree scan)
__global__ void scan1_k(const int* __restrict__ counts, int* incl, int* bsum, int n) {
    __shared__ int tmp[SCAN_B];
    int t = threadIdx.x;
    int i = blockIdx.x * SCAN_B + t;
    int v = (i < n) ? counts[i] : 0;
    tmp[t] = v;
    __syncthreads();
    for (int o = 1; o < SCAN_B; o <<= 1) {
        int x = 0;
        if (t >= o) x = tmp[t - o];
        __syncthreads();
        if (t >= o) tmp[t] += x;
        __syncthreads();
    }
    if (i < n) incl[i] = tmp[t];
    if (t == SCAN_B - 1) bsum[blockIdx.x] = tmp[t];
}

__global__ void scan2_k(const int* __restrict__ bsum, int* bscan, int nb) {
    __shared__ int tmp[SCAN_B];
    int t = threadIdx.x;
    tmp[t] = (t < nb) ? bsum[t] : 0;
    __syncthreads();
    for (int o = 1; o < SCAN_B; o <<= 1) {
        int x = 0;
        if (t >= o) x = tmp[t - o];
        __syncthreads();
        if (t >= o) tmp[t] += x;
        __syncthreads();
    }
    bscan[t] = tmp[t];
}

// Pass B epilogue: exclusive offsets ofs[i] = inclusive[i] + blockoff - hist[i]
__global__ void exclA_k(const int* __restrict__ incl, const int* __restrict__ bscan,
                        const int* __restrict__ hist, int* __restrict__ ofs, int len) {
    int i = blockIdx.x * 256 + threadIdx.x;
    if (i < len) {
        int boff = (blockIdx.x > 0) ? bscan[blockIdx.x - 1] : 0;
        ofs[i] = incl[i] + boff - hist[i];
    }
}

// Pass C: bucket-scatter packed (src,dst) pairs via LDS cursors
__global__ void scatC_k(const int* __restrict__ ei, const int* __restrict__ flag,
                        const int* __restrict__ ofs, long long* __restrict__ ebuf,
                        int E, int n, int NB, int NBUK, int shiftv) {
    __shared__ int cur[256];
    int blk = blockIdx.x;
    for (int b = threadIdx.x; b < NBUK; b += 256) cur[b] = ofs[b * NB + blk];
    __syncthreads();
    int e0 = blk * CH;
    int e1 = min(e0 + CH, E);
    int i64 = flag[0];
    for (int e = e0 + threadIdx.x; e < e1; e += 256) {
        int s, d;
        if (i64) {
            const long long* e64 = (const long long*)ei;
            s = (int)e64[e]; d = (int)e64[(size_t)E + e];
        } else {
            s = ei[e]; d = ei[(size_t)E + e];
        }
        int b = ((unsigned)d < (unsigned)n) ? min(d >> shiftv, NBUK - 1) : (NBUK - 1);
        int pos = atomicAdd(&cur[b], 1);
        ebuf[pos] = ((long long)(unsigned)d << 32) | (unsigned)s;
    }
}

// degree count on bucket-sorted pairs (L2-hot counters)
__global__ void count_ebuf_k(const long long* __restrict__ ebuf, int* counts, int E, int n) {
    int e = blockIdx.x * blockDim.x + threadIdx.x;
    if (e >= E) return;
    long long pr = ebuf[e];
    int d = (int)(pr >> 32);
    if ((unsigned)d < (unsigned)n) atomicAdd(&counts[d], 1);
}

__global__ void dinv_k(const int* __restrict__ counts, float* dinv, int n) {
    int i = blockIdx.x * blockDim.x + threadIdx.x;
    if (i < n) dinv[i] = rsqrtf((float)counts[i]);
}

__global__ void rowptr_k(const int* __restrict__ incl, const int* __restrict__ bscan,
                         int* rowptr, int n) {
    int i = blockIdx.x * blockDim.x + threadIdx.x;
    if (i < n) {
        int boff = (blockIdx.x > 0) ? bscan[blockIdx.x - 1] : 0;
        rowptr[i + 1] = incl[i] + boff;
        if (i == 0) rowptr[0] = 0;
    }
}

__global__ void cursor_k(const int* __restrict__ rowptr, int* cursor, int n) {
    int i = blockIdx.x * blockDim.x + threadIdx.x;
    if (i < n) cursor[i] = rowptr[i];
}

// Pass D: final CSR scatter from bucket-sorted pairs (dense col-window writes)
__global__ void scatD_k(const long long* __restrict__ ebuf, int* cursor,
                        int* __restrict__ col, int E, int n) {
    int e = blockIdx.x * blockDim.x + threadIdx.x;
    if (e < E) {
        long long pr = ebuf[e];
        int d = (int)(pr >> 32);
        int s = (int)(pr & 0xffffffffLL);
        if ((unsigned)s < (unsigned)n && (unsigned)d < (unsigned)n) {
            int pos = atomicAdd(&cursor[d], 1);
            col[pos] = s;
        }
    } else if (e < E + n) {
        int i = e - E;
        int pos = atomicAdd(&cursor[i], 1);
        col[pos] = i;
    }
}

// ---------------- bf16 MFMA GEMM: C[M,Nn] = A[M,K] * Bt[Nn,K]^T ----------------
#define TM 64
#define TN 64
#define BK 32
#define LDSS 40

__global__ __launch_bounds__(256) void gemm_bt_k(
    const u16* __restrict__ A, const u16* __restrict__ Bt,
    u16* __restrict__ C, int M, int K, int Nn) {
    __shared__ u16 As[TM * LDSS];
    __shared__ u16 Bs[TN * LDSS];
    int tid = threadIdx.x;
    int wave = tid >> 6;
    int lane = tid & 63;
    int wm = (wave & 1) * 32;
    int wn = (wave >> 1) * 32;
    int row0 = blockIdx.x * TM;
    int col0 = blockIdx.y * TN;

    f32x4 acc00 = {0.f, 0.f, 0.f, 0.f}, acc01 = acc00, acc10 = acc00, acc11 = acc00;

    int lrow = tid >> 2;
    int lcol = (tid & 3) * 8;
    int q = lane >> 4;
    int m = lane & 15;

    for (int k0 = 0; k0 < K; k0 += BK) {
        int gr = row0 + lrow;
        us8 va = (us8)0;
        if (gr < M) va = *(const us8*)(A + (size_t)gr * K + k0 + lcol);
        *(us8*)(&As[lrow * LDSS + lcol]) = va;
        int gc = col0 + lrow;
        us8 vb = (us8)0;
        if (gc < Nn) vb = *(const us8*)(Bt + (size_t)gc * K + k0 + lcol);
        *(us8*)(&Bs[lrow * LDSS + lcol]) = vb;
        __syncthreads();

        us8 a0 = *(const us8*)(&As[(wm + m) * LDSS + q * 8]);
        us8 a1 = *(const us8*)(&As[(wm + 16 + m) * LDSS + q * 8]);
        us8 b0 = *(const us8*)(&Bs[(wn + m) * LDSS + q * 8]);
        us8 b1 = *(const us8*)(&Bs[(wn + 16 + m) * LDSS + q * 8]);
        bf8 fa0 = __builtin_bit_cast(bf8, a0);
        bf8 fa1 = __builtin_bit_cast(bf8, a1);
        bf8 fb0 = __builtin_bit_cast(bf8, b0);
        bf8 fb1 = __builtin_bit_cast(bf8, b1);
        acc00 = __builtin_amdgcn_mfma_f32_16x16x32_bf16(fa0, fb0, acc00, 0, 0, 0);
        acc01 = __builtin_amdgcn_mfma_f32_16x16x32_bf16(fa0, fb1, acc01, 0, 0, 0);
        acc10 = __builtin_amdgcn_mfma_f32_16x16x32_bf16(fa1, fb0, acc10, 0, 0, 0);
        acc11 = __builtin_amdgcn_mfma_f32_16x16x32_bf16(fa1, fb1, acc11, 0, 0, 0);
        __syncthreads();
    }

    int cn = lane & 15;
    // C/D layout: col = lane&15, row = (lane>>4)*4 + r  [measured m89]
    #pragma unroll
    for (int r = 0; r < 4; r++) {
        int rr = q * 4 + r;
        int row_a = row0 + wm + rr;
        int row_b = row0 + wm + 16 + rr;
        if (row_a < M) {
            C[(size_t)row_a * Nn + col0 + wn + cn] = f2bf(acc00[r]);
            C[(size_t)row_a * Nn + col0 + wn + 16 + cn] = f2bf(acc01[r]);
        }
        if (row_b < M) {
            C[(size_t)row_b * Nn + col0 + wn + cn] = f2bf(acc10[r]);
            C[(size_t)row_b * Nn + col0 + wn + 16 + cn] = f2bf(acc11[r]);
        }
    }
}

// ---------------- wave-per-node aggregate [+ bias + LN + ELU (+resid) (+classifier)] ---
__global__ __launch_bounds__(256) void agg_k(
    const u16* __restrict__ in, const int* __restrict__ rowptr,
    const int* __restrict__ col, const float* __restrict__ dinv,
    const float* __restrict__ bias, const float* __restrict__ gamma,
    const float* __restrict__ beta, u16* __restrict__ out_h,
    const u16* __restrict__ resid, void* __restrict__ final_base,
    const int* __restrict__ flag, const float* __restrict__ Wcf,
    const float* __restrict__ bcf, int F, int nN) {
    int wv = threadIdx.x >> 6;
    int lane = threadIdx.x & 63;
    int i = blockIdx.x * 4 + wv;
    if (i >= nN) return;

    int rowt = F >> 3;                    // 32 (F=256) or 16 (F=128)
    int Gw = 64 / rowt;                   // 2 or 4 edge groups per wave
    int g = lane / rowt;
    int f0 = (lane & (rowt - 1)) << 3;

    int beg = rowptr[i], end = rowptr[i + 1];
    f32x8 acc = {0, 0, 0, 0, 0, 0, 0, 0}, acc2 = acc;
    int e = beg + g;
    for (; e + Gw < end; e += 2 * Gw) {
        int s0 = col[e], s1 = col[e + Gw];
        s0 = ((unsigned)s0 < (unsigned)nN) ? s0 : 0;
        s1 = ((unsigned)s1 < (unsigned)nN) ? s1 : 0;
        float w0 = dinv[s0], w1 = dinv[s1];
        us8 v0 = *(const us8*)(in + (unsigned)(s0 * F) + f0);
        us8 v1 = *(const us8*)(in + (unsigned)(s1 * F) + f0);
        fma8(acc, w0, v0);
        fma8(acc2, w1, v1);
    }
    if (e < end) {
        int s = col[e];
        s = ((unsigned)s < (unsigned)nN) ? s : 0;
        us8 v = *(const us8*)(in + (unsigned)(s * F) + f0);
        fma8(acc, dinv[s], v);
    }
    #pragma unroll
    for (int j = 0; j < 8; j++) acc[j] += acc2[j];

    for (int o = 32; o >= rowt; o >>= 1) {
        #pragma unroll
        for (int j = 0; j < 8; j++) acc[j] += __shfl_down(acc[j], o);
    }
    bool active = lane < rowt;
    float di = dinv[i];

    if (!bias) {  // plain mode (layer-2 pre-aggregate)
        if (active) {
            us8 o8;
            #pragma unroll
            for (int j = 0; j < 8; j++) o8[j] = f2bf(di * acc[j]);
            *(us8*)(out_h + (unsigned)(i * F) + f0) = o8;
        }
        return;
    }

    f32x8 accv = {0, 0, 0, 0, 0, 0, 0, 0};
    if (active) {
        #pragma unroll
        for (int j = 0; j < 8; j++) accv[j] = di * acc[j] + bias[f0 + j];
    }
    int f32m = final_base ? flag[1] : 0;
    if (final_base && active) {
        size_t conv_idx = (size_t)nN * 4 + (size_t)i * F + f0;
        if (f32m) {
            #pragma unroll
            for (int j = 0; j < 8; j++) ((float*)final_base)[conv_idx + j] = accv[j];
        } else {
            us8 o8;
            #pragma unroll
            for (int j = 0; j < 8; j++) o8[j] = f2bf(accv[j]);
            *(us8*)((u16*)final_base + conv_idx) = o8;
        }
    }

    float p1 = 0.f, p2 = 0.f;
    #pragma unroll
    for (int j = 0; j < 8; j++) { p1 += accv[j]; p2 += accv[j] * accv[j]; }
    for (int o = rowt >> 1; o >= 1; o >>= 1) {
        p1 += __shfl_xor(p1, o);
        p2 += __shfl_xor(p2, o);
    }
    float invF = 1.0f / (float)F;
    float mu = p1 * invF;
    float var = fmaxf(p2 * invF - mu * mu, 0.f);
    float rstd = rsqrtf(var + 1e-5f);

    f32x8 h8 = {0, 0, 0, 0, 0, 0, 0, 0};
    if (active) {
        f32x8 y8;
        #pragma unroll
        for (int j = 0; j < 8; j++)
            y8[j] = (accv[j] - mu) * rstd * gamma[f0 + j] + beta[f0 + j];
        if (final_base) {
            size_t bn_idx = (size_t)nN * 4 + (size_t)nN * F + (size_t)i * F + f0;
            if (f32m) {
                #pragma unroll
                for (int j = 0; j < 8; j++) ((float*)final_base)[bn_idx + j] = y8[j];
            } else {
                us8 o8;
                #pragma unroll
                for (int j = 0; j < 8; j++) o8[j] = f2bf(y8[j]);
                *(us8*)((u16*)final_base + bn_idx) = o8;
            }
        }
        #pragma unroll
        for (int j = 0; j < 8; j++) h8[j] = (y8[j] > 0.f) ? y8[j] : expm1f(y8[j]);
        if (resid) {
            us8 r8 = *(const us8*)(resid + (unsigned)(i * F) + f0);
            #pragma unroll
            for (int j = 0; j < 8; j++) h8[j] += bf2f(r8[j]);
        }
        if (out_h) {
            us8 o8;
            #pragma unroll
            for (int j = 0; j < 8; j++) o8[j] = f2bf(h8[j]);
            *(us8*)(out_h + (unsigned)(i * F) + f0) = o8;
        }
    }

    if (Wcf) {
        float s0 = 0.f, s1 = 0.f, s2 = 0.f, s3 = 0.f;
        if (active) {
            #pragma unroll
            for (int j = 0; j < 8; j++) {
                const float* wr = Wcf + (f0 + j) * 4;
                s0 += h8[j] * wr[0];
                s1 += h8[j] * wr[1];
                s2 += h8[j] * wr[2];
                s3 += h8[j] * wr[3];
            }
        }
        for (int o = rowt >> 1; o >= 1; o >>= 1) {
            s0 += __shfl_xor(s0, o);
            s1 += __shfl_xor(s1, o);
            s2 += __shfl_xor(s2, o);
            s3 += __shfl_xor(s3, o);
        }
        if (lane == 0) {
            size_t lidx = (size_t)i * 4;
            if (f32m) {
                ((float*)final_base)[lidx + 0] = s0 + bcf[0];
                ((float*)final_base)[lidx + 1] = s1 + bcf[1];
                ((float*)final_base)[lidx + 2] = s2 + bcf[2];
                ((float*)final_base)[lidx + 3] = s3 + bcf[3];
            } else {
                ((u16*)final_base)[lidx + 0] = f2bf(s0 + bcf[0]);
                ((u16*)final_base)[lidx + 1] = f2bf(s1 + bcf[1]);
                ((u16*)final_base)[lidx + 2] = f2bf(s2 + bcf[2]);
                ((u16*)final_base)[lidx + 3] = f2bf(s3 + bcf[3]);
            }
        }
    }
}

// ---------------- standalone bias + LayerNorm + ELU in place (layer 2, F=512) ----------
__global__ void ln_elu_k(u16* __restrict__ h, const float* __restrict__ bias,
                         const float* __restrict__ gamma,
                         const float* __restrict__ beta, int F) {
    int i = blockIdx.x;
    int f = threadIdx.x;
    size_t idx = (size_t)i * F + f;
    float v = bf2f(h[idx]) + (bias ? bias[f] : 0.f);
    float p1 = v, p2 = v * v;
    #pragma unroll
    for (int o = 32; o >= 1; o >>= 1) {
        p1 += __shfl_down(p1, o);
        p2 += __shfl_down(p2, o);
    }
    __shared__ float red1[8], red2[8], stats[2];
    int lane = threadIdx.x & 63, w = threadIdx.x >> 6;
    if (lane == 0) { red1[w] = p1; red2[w] = p2; }
    __syncthreads();
    if (threadIdx.x == 0) {
        float t1 = 0.f, t2 = 0.f;
        int nw = blockDim.x >> 6;
        for (int j = 0; j < nw; j++) { t1 += red1[j]; t2 += red2[j]; }
        float invF = 1.0f / (float)F;
        float mu = t1 * invF;
        float var = fmaxf(t2 * invF - mu * mu, 0.f);
        stats[0] = mu;
        stats[1] = rsqrtf(var + 1e-5f);
    }
    __syncthreads();
    float y = (v - stats[0]) * stats[1] * gamma[f] + beta[f];
    float hh = (y > 0.f) ? y : expm1f(y);
    h[idx] = f2bf(hh);
}

// ---------------- ws-too-small marker ----------------
__global__ void marker_k(float* out) {
    if (threadIdx.x == 0 && blockIdx.x == 0) {
        out[0] = 31337.0f; out[1] = 31337.0f;
    }
}

extern "C" void kernel_launch(void* const* d_in, const int* in_sizes, int n_in,
                              void* d_out, int out_size, void* d_ws, size_t ws_size,
                              hipStream_t stream) {
    const int N = in_sizes[0] / 512;   // 50000
    const int E = in_sizes[1] / 2;     // 1600000

    const void* x  = d_in[0];
    const int* ei  = (const int*)d_in[1];

    // ---- workspace carve ----
    char* p = (char*)d_ws;
    auto alloc = [&](size_t bytes) -> void* {
        void* r = (void*)p;
        p += (bytes + 255) & ~(size_t)255;
        return r;
    };
    int*   flag   = (int*)alloc(256);
    int*   counts = (int*)alloc((size_t)N * 4);
    int*   rowptr = (int*)alloc((size_t)(N + 1) * 4);
    int*   cursor = (int*)alloc((size_t)N * 4);
    int*   incl   = (int*)alloc((size_t)N * 4);
    int*   bsum   = (int*)alloc(256 * 4);
    int*   bscan  = (int*)alloc(256 * 4);
    float* dinv   = (float*)alloc((size_t)N * 4);
    int*   col    = (int*)alloc((size_t)(E + N) * 4);
    float* pbuf   = (float*)alloc(4096 * 4);
    u16* W1t = (u16*)alloc((size_t)512 * 256 * 2);
    u16* W2t = (u16*)alloc((size_t)256 * 512 * 2);
    u16* W3t = (u16*)alloc((size_t)512 * 256 * 2);
    u16* W4t = (u16*)alloc((size_t)256 * 128 * 2);
    u16* bigA = (u16*)alloc((size_t)N * 512 * 2);  // xbf -> h2
    u16* xw   = (u16*)alloc((size_t)N * 256 * 2);  // ebuf (CSR build) -> GEMM scratch
    u16* h1   = (u16*)alloc((size_t)N * 256 * 2);  // hist arrays (CSR build) -> h1

    size_t needed = (size_t)(p - (char*)d_ws);
    if (needed > ws_size) {
        marker_k<<<1, 64, 0, stream>>>((float*)d_out);
        return;
    }

    u16* xbf = bigA;
    u16* h2  = bigA;  // [N,512], alive after xbf dead

    // bucket-sort params (dead buffers aliased; all CSR work precedes their next use)
    int shiftv = 8;
    while (((N - 1) >> shiftv) > 255) shiftv++;
    int NBUK = ((N - 1) >> shiftv) + 1;            // 196 for N=50000
    int NB_E = (E + CH - 1) / CH;                  // 196 for E=1.6M
    int flatlen = NBUK * NB_E;                     // ~38k
    int NH = (flatlen + 255) / 256;                // <=256 required
    long long* ebuf = (long long*)xw;              // E*8 B <= N*256*2 B
    int* hist     = (int*)h1;
    int* histincl = hist + flatlen;
    int* ofs      = histincl + flatlen;

    PTab tab;
    tab.e[0]  = { d_in[3],  256, 0    };  // b1
    tab.e[1]  = { d_in[12], 256, 256  };  // g1
    tab.e[2]  = { d_in[13], 256, 512  };  // be1
    tab.e[3]  = { d_in[5],  512, 768  };  // b2
    tab.e[4]  = { d_in[14], 512, 1280 };  // g2
    tab.e[5]  = { d_in[15], 512, 1792 };  // be2
    tab.e[6]  = { d_in[7],  256, 2304 };  // b3
    tab.e[7]  = { d_in[16], 256, 2560 };  // g3
    tab.e[8]  = { d_in[17], 256, 2816 };  // be3
    tab.e[9]  = { d_in[9],  128, 3072 };  // b4
    tab.e[10] = { d_in[18], 128, 3200 };  // g4
    tab.e[11] = { d_in[19], 128, 3328 };  // be4
    tab.e[12] = { d_in[10], 512, 3456 };  // Wc
    tab.e[13] = { d_in[11], 4,   3968 };  // bc
    float* b1f = pbuf + 0,   *g1f = pbuf + 256,  *be1f = pbuf + 512;
    float* b2f = pbuf + 768, *g2f = pbuf + 1280, *be2f = pbuf + 1792;
    float* b3f = pbuf + 2304,*g3f = pbuf + 2560, *be3f = pbuf + 2816;
    float* b4f = pbuf + 3072,*g4f = pbuf + 3200, *be4f = pbuf + 3328;
    float* Wcf = pbuf + 3456,*bcf = pbuf + 3968;

    int nb1 = (N + 255) / 256;
    int NB = (N + SCAN_B - 1) / SCAN_B;

    // ---- dtype probes ----
    detect_k<<<1, 256, 0, stream>>>(ei, E, (const u16*)x, flag);

    // ---- canonicalize ----
    cvt_x_k<<<4096, 256, 0, stream>>>(x, xbf, (long)N * 512 / 4, flag);
    cvt_wt_k<<<(512 * 256 + 255) / 256, 256, 0, stream>>>(d_in[2], W1t, 512, 256, flag);
    cvt_wt_k<<<(256 * 512 + 255) / 256, 256, 0, stream>>>(d_in[4], W2t, 256, 512, flag);
    cvt_wt_k<<<(512 * 256 + 255) / 256, 256, 0, stream>>>(d_in[6], W3t, 512, 256, flag);
    cvt_wt_k<<<(256 * 128 + 255) / 256, 256, 0, stream>>>(d_in[8], W4t, 256, 128, flag);
    cvt_params_k<<<14, 256, 0, stream>>>(tab, pbuf, flag);

    // ---- CSR build (bucket-sorted) ----
    histA_k<<<NB_E, 256, 0, stream>>>(ei, flag, hist, E, N, NB_E, NBUK, shiftv);
    scan1_k<<<NH, SCAN_B, 0, stream>>>(hist, histincl, bsum, flatlen);
    scan2_k<<<1, SCAN_B, 0, stream>>>(bsum, bscan, NH);
    exclA_k<<<NH, 256, 0, stream>>>(histincl, bscan, hist, ofs, flatlen);
    scatC_k<<<NB_E, 256, 0, stream>>>(ei, flag, ofs, ebuf, E, N, NB_E, NBUK, shiftv);
    init_counts_k<<<nb1, 256, 0, stream>>>(counts, N);
    count_ebuf_k<<<(E + 255) / 256, 256, 0, stream>>>(ebuf, counts, E, N);
    dinv_k<<<nb1, 256, 0, stream>>>(counts, dinv, N);
    scan1_k<<<NB, SCAN_B, 0, stream>>>(counts, incl, bsum, N);
    scan2_k<<<1, SCAN_B, 0, stream>>>(bsum, bscan, NB);
    rowptr_k<<<NB, SCAN_B, 0, stream>>>(incl, bscan, rowptr, N);
    cursor_k<<<nb1, 256, 0, stream>>>(rowptr, cursor, N);
    scatD_k<<<(E + N + 255) / 256, 256, 0, stream>>>(ebuf, cursor, col, E, N);

    int gx = (N + TM - 1) / TM;
    int ga = (N + 3) / 4;

    // ---- layer 1: xbf[N,512] @ W1 -> agg+LN+ELU -> h1[N,256] ----
    gemm_bt_k<<<dim3(gx, 256 / TN), 256, 0, stream>>>(xbf, W1t, xw, N, 512, 256);
    agg_k<<<ga, 256, 0, stream>>>(xw, rowptr, col, dinv, b1f, g1f, be1f,
                                  h1, nullptr, nullptr, flag, nullptr, nullptr, 256, N);
    // ---- layer 2 (agg BEFORE GEMM: agg(h1 @ W2) == agg(h1) @ W2) ----
    agg_k<<<ga, 256, 0, stream>>>(h1, rowptr, col, dinv, nullptr, nullptr, nullptr,
                                  xw, nullptr, nullptr, flag, nullptr, nullptr, 256, N);
    gemm_bt_k<<<dim3(gx, 512 / TN), 256, 0, stream>>>(xw, W2t, h2, N, 256, 512);
    ln_elu_k<<<N, 512, 0, stream>>>(h2, b2f, g2f, be2f, 512);
    // ---- layer 3: h2[N,512] @ W3 -> agg+LN+ELU + h1 -> h1[N,256] ----
    gemm_bt_k<<<dim3(gx, 256 / TN), 256, 0, stream>>>(h2, W3t, xw, N, 512, 256);
    agg_k<<<ga, 256, 0, stream>>>(xw, rowptr, col, dinv, b3f, g3f, be3f,
                                  h1, h1, nullptr, flag, nullptr, nullptr, 256, N);
    // ---- layer 4: h1[N,256] @ W4 -> agg -> out_conv/out_bn + fused classifier ----
    gemm_bt_k<<<dim3(gx, 128 / TN), 256, 0, stream>>>(h1, W4t, xw, N, 256, 128);
    agg_k<<<ga, 256, 0, stream>>>(xw, rowptr, col, dinv, b4f, g4f, be4f,
                                  nullptr, nullptr, d_out, flag, Wcf, bcf, 128, N);
}